// Round 15
// baseline (75.761 us; speedup 1.0000x reference)
//
#include <hip/hip_runtime.h>
#include <hip/hip_bf16.h>
#include <math.h>

// Problem constants (B,C,H,W = 4,64,64,64)
#define B_   4
#define C_   64
#define N_   4096   // H*W
#define C2_  128

using frag  = __attribute__((ext_vector_type(8))) short;  // 8 bf16 (4 VGPRs)
using f32x4 = __attribute__((ext_vector_type(4))) float;
using f4    = __attribute__((ext_vector_type(4))) float;

__device__ __forceinline__ unsigned short f2bf(float f) {
  unsigned int u = __float_as_uint(f);
  u += 0x7fffu + ((u >> 16) & 1u);   // RNE
  return (unsigned short)(u >> 16);
}
__device__ __forceinline__ float bf2f(unsigned short h) {
  return __uint_as_float(((unsigned int)h) << 16);
}
// pack 2 floats -> 2 bf16 in one u32 (compiler fuses to v_cvt_pk_bf16_f32)
__device__ __forceinline__ unsigned int pkbf(float a, float b) {
  __hip_bfloat16 ha = __float2bfloat16(a), hb = __float2bfloat16(b);
  unsigned short ua, ub;
  __builtin_memcpy(&ua, &ha, 2);
  __builtin_memcpy(&ub, &hb, 2);
  return (unsigned int)ua | ((unsigned int)ub << 16);
}
// 8 fp32 -> bf16 A/B fragment
__device__ __forceinline__ frag pk8(f4 lo, f4 hi) {
  frag f;
  unsigned int* u = (unsigned int*)&f;
  u[0] = pkbf(lo.x, lo.y);
  u[1] = pkbf(lo.z, lo.w);
  u[2] = pkbf(hi.x, hi.y);
  u[3] = pkbf(hi.z, hi.w);
  return f;
}
__device__ __forceinline__ f4 max4(f4 a, f4 b) {
  return (f4){fmaxf(a.x, b.x), fmaxf(a.y, b.y), fmaxf(a.z, b.z), fmaxf(a.w, b.w)};
}

// ---------------------------------------------------------------------------
// prep + cx fused (r12): stage x1,x2 64-n tiles once; emit a1t,a2t bf16
// [N][C]; cx partial via MFMA from the SAME LDS tiles.
// ---------------------------------------------------------------------------
__global__ __launch_bounds__(256) void prep_kernel(const float* __restrict__ x1,
                                                   const float* __restrict__ x2,
                                                   unsigned short* __restrict__ a1t,
                                                   unsigned short* __restrict__ a2t,
                                                   float* __restrict__ cxp) {
  __shared__ float tA[64 * 65];   // x2
  __shared__ float tB[64 * 65];   // x1
  int b = blockIdx.y, n0 = blockIdx.x * 64, tid = threadIdx.x;
  int wave = tid >> 6, lane = tid & 63, l16 = lane & 15, lq = lane >> 4;
  {
    int n = tid & 63, cq = tid >> 6;
#pragma unroll
    for (int k = 0; k < 16; ++k) {
      int c = cq + 4 * k;
      tA[c * 65 + n] = x2[((size_t)(b * C_ + c)) * N_ + n0 + n];   // coalesced
      tB[c * 65 + n] = x1[((size_t)(b * C_ + c)) * N_ + n0 + n];
    }
  }
  __syncthreads();
  {  // transpose-out (stride-65 conflict-free reads, coalesced writes)
    int c = tid & 63, nq = tid >> 6;
#pragma unroll
    for (int k = 0; k < 16; ++k) {
      int n2 = nq + 4 * k;
      a2t[((size_t)b * N_ + n0 + n2) * C_ + c] = f2bf(tA[c * 65 + n2]);
      a1t[((size_t)b * N_ + n0 + n2) * C_ + c] = f2bf(tB[c * 65 + n2]);
    }
  }
  {  // cx partial via MFMA: cxp[d*64+c] = sum_n x2[d][n]*x1[c][n]
    int dd = 16 * wave + l16;
    frag afr[2];
#pragma unroll
    for (int ks = 0; ks < 2; ++ks) {
      float w0[8];
#pragma unroll
      for (int j = 0; j < 8; ++j) w0[j] = tA[dd * 65 + ks * 32 + lq * 8 + j];
      afr[ks] = pk8((f4){w0[0], w0[1], w0[2], w0[3]}, (f4){w0[4], w0[5], w0[6], w0[7]});
    }
    f32x4 acc[4];
#pragma unroll
    for (int cg = 0; cg < 4; ++cg) acc[cg] = (f32x4){0.f, 0.f, 0.f, 0.f};
#pragma unroll
    for (int cg = 0; cg < 4; ++cg) {
      int cc = cg * 16 + l16;
#pragma unroll
      for (int ks = 0; ks < 2; ++ks) {
        float w0[8];
#pragma unroll
        for (int j = 0; j < 8; ++j) w0[j] = tB[cc * 65 + ks * 32 + lq * 8 + j];
        frag bfr = pk8((f4){w0[0], w0[1], w0[2], w0[3]}, (f4){w0[4], w0[5], w0[6], w0[7]});
        acc[cg] = __builtin_amdgcn_mfma_f32_16x16x32_bf16(afr[ks], bfr, acc[cg], 0, 0, 0);
      }
    }
    float* op = cxp + ((size_t)(b * 64 + blockIdx.x)) * 4096;
#pragma unroll
    for (int cg = 0; cg < 4; ++cg)
#pragma unroll
      for (int r = 0; r < 4; ++r)
        op[(16 * wave + 4 * lq + r) * 64 + cg * 16 + l16] = acc[cg][r];
  }
}

// ---------------------------------------------------------------------------
// support via MFMA: vT[d][n] = sum_c W[c][d] * a2t[n][c].  Grid (128, B).
// ---------------------------------------------------------------------------
__global__ __launch_bounds__(256) void support_mm_kernel(const float* __restrict__ weight,
                                                         const unsigned short* __restrict__ a2t,
                                                         unsigned short* __restrict__ vT) {
  __shared__ float Wl[64 * 65];   // [c][d] fp32, padded
  int b = blockIdx.y, n0 = blockIdx.x * 32, tid = threadIdx.x;
  int wave = tid >> 6, lane = tid & 63, l16 = lane & 15, lq = lane >> 4;
#pragma unroll
  for (int k = 0; k < 16; ++k) {
    int lin = tid + 256 * k;
    Wl[(lin >> 6) * 65 + (lin & 63)] = weight[lin];   // coalesced, cf banks
  }
  frag b0[2], b1[2];
#pragma unroll
  for (int ng = 0; ng < 2; ++ng) {
    const unsigned short* bp = a2t + ((size_t)b * N_ + n0 + ng * 16 + l16) * C_;
    b0[ng] = *(const frag*)(bp + lq * 8);
    b1[ng] = *(const frag*)(bp + 32 + lq * 8);
  }
  __syncthreads();
  int dd = 16 * wave + l16;
  frag aw[2];
#pragma unroll
  for (int ks = 0; ks < 2; ++ks) {
    float wv[8];
#pragma unroll
    for (int j = 0; j < 8; ++j) wv[j] = Wl[(ks * 32 + lq * 8 + j) * 65 + dd];  // 2-way (free)
    aw[ks] = pk8((f4){wv[0], wv[1], wv[2], wv[3]}, (f4){wv[4], wv[5], wv[6], wv[7]});
  }
  f32x4 acc[2];
#pragma unroll
  for (int ng = 0; ng < 2; ++ng) {
    acc[ng] = (f32x4){0.f, 0.f, 0.f, 0.f};
    acc[ng] = __builtin_amdgcn_mfma_f32_16x16x32_bf16(aw[0], b0[ng], acc[ng], 0, 0, 0);
    acc[ng] = __builtin_amdgcn_mfma_f32_16x16x32_bf16(aw[1], b1[ng], acc[ng], 0, 0, 0);
  }
#pragma unroll
  for (int ng = 0; ng < 2; ++ng)
#pragma unroll
    for (int r = 0; r < 4; ++r)
      vT[((size_t)(b * C_) + 16 * wave + 4 * lq + r) * N_ + n0 + ng * 16 + l16] =
          f2bf(acc[ng][r]);
}

// cx reduce: cx[b][idx] = sum_seg cxp[b][seg][idx]   (cxT layout [d][c])
__global__ __launch_bounds__(256) void cxred_kernel(const float* __restrict__ cxp,
                                                    float* __restrict__ cx) {
  int idx = blockIdx.x * 256 + threadIdx.x;   // 0..16383
  int b = idx >> 12, r = idx & 4095;
  const float* p = cxp + (size_t)b * 64 * 4096 + r;
  float s = 0.f;
#pragma unroll 8
  for (int sg = 0; sg < 64; ++sg) s += p[(size_t)sg * 4096];
  cx[idx] = s;
}

// ---------------------------------------------------------------------------
// s2bf: s2[b][c][e] = sum_d cxT[d][c] * w2[d][e]  -> bf16 row-major [c][e]
// NOTE: s2bf buffer aliases a2t -> must run AFTER attn.
// ---------------------------------------------------------------------------
__global__ __launch_bounds__(256) void s2bf_kernel(const float* __restrict__ cx,
                                                   const float* __restrict__ w2,
                                                   unsigned short* __restrict__ s2bf) {
  __shared__ float cxl[4096];
  __shared__ float w2l[4096];
  int b = blockIdx.x, tid = threadIdx.x;
#pragma unroll
  for (int k = 0; k < 16; ++k) {
    int lin = tid + 256 * k;
    cxl[lin] = cx[(size_t)b * 4096 + lin];
    w2l[lin] = w2[lin];
  }
  __syncthreads();
  int c = tid & 63, eg = tid >> 6;
  float acc[16];
#pragma unroll
  for (int i = 0; i < 16; ++i) acc[i] = 0.f;
  for (int d = 0; d < 64; ++d) {
    float a = cxl[d * 64 + c];                               // per-lane cf
#pragma unroll
    for (int i = 0; i < 16; ++i) acc[i] += a * w2l[d * 64 + eg * 16 + i];  // broadcast
  }
  unsigned short* op = s2bf + (size_t)b * 4096 + c * 64 + eg * 16;
#pragma unroll
  for (int i = 0; i < 8; ++i)
    *(unsigned int*)(op + 2 * i) = pkbf(acc[2 * i], acc[2 * i + 1]);
}

// ---------------------------------------------------------------------------
// Flash attention, 8-wave blocks (QBLK=128, 16 q/wave), KV-split SEG,
// swapped QK^T, defer-max, KV tile 64, register dbuf staging, one barrier
// per tile. (r12/r14 kernel, unchanged.)
// ---------------------------------------------------------------------------
template <int SEG>
__global__ __launch_bounds__(512) void attn_kernel(const unsigned short* __restrict__ a1t,
                                                   const unsigned short* __restrict__ a2t,
                                                   const unsigned short* __restrict__ vT,
                                                   float* __restrict__ z,
                                                   unsigned short* __restrict__ Opart,
                                                   float* __restrict__ ml) {
  __shared__ unsigned short Kt[2][64 * 64];    // [m][c] bf16, row-XOR-swizzled
  __shared__ unsigned short Vt[2][64 * 64];    // [d][m] bf16, row-XOR-swizzled
  __shared__ uint2 Pl[8][16 * 16];             // per-wave P [q][kv] bf16, swizzled

  const int b = blockIdx.y, n0 = blockIdx.x * 128, tid = threadIdx.x;
  const int seg = (SEG > 1) ? blockIdx.z : 0;
  const int wave = tid >> 6, lane = tid & 63;
  const int l16 = lane & 15, lq = lane >> 4;
  const int NT = N_ / SEG / 64;
  const int mbase = seg * (N_ / SEG);

  const unsigned short* qbase = a1t + ((size_t)b * N_ + n0 + wave * 16 + l16) * C_;
  frag qa0 = *(const frag*)(qbase + lq * 8);
  frag qa1 = *(const frag*)(qbase + 32 + lq * 8);

  f32x4 O[4];
#pragma unroll
  for (int i = 0; i < 4; ++i) O[i] = (f32x4){0.f, 0.f, 0.f, 0.f};
  float m_l = -1e30f, l_l = 0.f;   // running max/sum for q = l16 (replicated x4)

  const unsigned short* a2b = a2t + (size_t)b * N_ * C_;
  const unsigned short* vTb = vT + (size_t)b * C_ * N_;
  char* Pw = (char*)&Pl[wave][0];
  const int swzP = (l16 & 7) << 4;

  // staging: 512 threads x 1 K-frag + 1 V-frag per tile
  const int srow = tid >> 3, scb = tid & 7;
  const int kswz = (scb * 16) ^ ((srow & 7) << 4);

  // prologue: stage tile 0
  frag k0 = *(const frag*)(a2b + (size_t)(mbase + srow) * C_ + scb * 8);
  frag v0 = *(const frag*)(vTb + (size_t)srow * N_ + mbase + scb * 8);
  *(frag*)((char*)&Kt[0][0] + srow * 128 + kswz) = k0;
  *(frag*)((char*)&Vt[0][0] + srow * 128 + kswz) = v0;
  __syncthreads();

  int cur = 0;
  for (int t = 0; t < NT; ++t, cur ^= 1) {
    // T14 issue-early: next tile's global loads in flight during compute
    if (t + 1 < NT) {
      int mn = mbase + (t + 1) * 64;
      k0 = *(const frag*)(a2b + (size_t)(mn + srow) * C_ + scb * 8);
      v0 = *(const frag*)(vTb + (size_t)srow * N_ + mn + scb * 8);
    }

    // S^T = K Q^T (swapped): lane holds S[kv=16ms+4lq+r][q=l16]
    f32x4 S[4];
    __builtin_amdgcn_s_setprio(1);
#pragma unroll
    for (int ms = 0; ms < 4; ++ms) {
      int m = ms * 16 + l16;
      int swz = (m & 7) << 4;
      frag kb0 = *(const frag*)((char*)&Kt[cur][0] + m * 128 + ((lq * 16) ^ swz));
      frag kb1 = *(const frag*)((char*)&Kt[cur][0] + m * 128 + ((64 + lq * 16) ^ swz));
      f32x4 acc = (f32x4){0.f, 0.f, 0.f, 0.f};
      acc = __builtin_amdgcn_mfma_f32_16x16x32_bf16(kb0, qa0, acc, 0, 0, 0);
      acc = __builtin_amdgcn_mfma_f32_16x16x32_bf16(kb1, qa1, acc, 0, 0, 0);
      S[ms] = acc;
    }
    __builtin_amdgcn_s_setprio(0);

    // lane-local row max (16 values) + 2-shuffle cross-lq reduce
    float mx0 = fmaxf(fmaxf(S[0][0], S[0][1]), fmaxf(S[0][2], S[0][3]));
    float mx1 = fmaxf(fmaxf(S[1][0], S[1][1]), fmaxf(S[1][2], S[1][3]));
    float mx2 = fmaxf(fmaxf(S[2][0], S[2][1]), fmaxf(S[2][2], S[2][3]));
    float mx3 = fmaxf(fmaxf(S[3][0], S[3][1]), fmaxf(S[3][2], S[3][3]));
    float mx = fmaxf(fmaxf(mx0, mx1), fmaxf(mx2, mx3));
    mx = fmaxf(mx, __shfl_xor(mx, 16, 64));
    mx = fmaxf(mx, __shfl_xor(mx, 32, 64));

    // defer-max: rescale only if some row grew by > 8
    if (!__all(mx <= m_l + 8.f)) {
      float mn = fmaxf(m_l, mx);
      float sc = __expf(m_l - mn);
      m_l = mn;
      l_l *= sc;
      float scb_[4];
#pragma unroll
      for (int r = 0; r < 4; ++r) scb_[r] = __shfl(sc, 20 * lq + r, 64);  // sc for O-row 4lq+r
#pragma unroll
      for (int ds = 0; ds < 4; ++ds)
#pragma unroll
        for (int r = 0; r < 4; ++r) O[ds][r] *= scb_[r];
    }

    // P = exp(S - m), lane-local row sum + 2 shuffles
    float p[16];
    float rs = 0.f;
#pragma unroll
    for (int ms = 0; ms < 4; ++ms)
#pragma unroll
      for (int r = 0; r < 4; ++r) {
        float e = __expf(S[ms][r] - m_l);
        p[ms * 4 + r] = e;
        rs += e;
      }
    rs += __shfl_xor(rs, 16, 64);
    rs += __shfl_xor(rs, 32, 64);
    l_l += rs;

    // P -> per-wave LDS: 4x ds_write_b64 (packed bf16), [q][kv] swizzled
#pragma unroll
    for (int ms = 0; ms < 4; ++ms) {
      uint2 w;
      w.x = pkbf(p[ms * 4 + 0], p[ms * 4 + 1]);
      w.y = pkbf(p[ms * 4 + 2], p[ms * 4 + 3]);
      *(uint2*)(Pw + l16 * 128 + ((32 * ms + 8 * lq) ^ swzP)) = w;
    }
    asm volatile("s_waitcnt lgkmcnt(0)" ::: "memory");
    __builtin_amdgcn_sched_barrier(0);  // rule 18: keep reads below the wait

    // O += P V
    frag pa0 = *(const frag*)(Pw + l16 * 128 + ((lq * 16) ^ swzP));
    frag pa1 = *(const frag*)(Pw + l16 * 128 + ((64 + lq * 16) ^ swzP));
    __builtin_amdgcn_s_setprio(1);
#pragma unroll
    for (int ds = 0; ds < 4; ++ds) {
      int d = ds * 16 + l16;
      int swz = (d & 7) << 4;
      frag vb0 = *(const frag*)((char*)&Vt[cur][0] + d * 128 + ((lq * 16) ^ swz));
      frag vb1 = *(const frag*)((char*)&Vt[cur][0] + d * 128 + ((64 + lq * 16) ^ swz));
      O[ds] = __builtin_amdgcn_mfma_f32_16x16x32_bf16(pa0, vb0, O[ds], 0, 0, 0);
      O[ds] = __builtin_amdgcn_mfma_f32_16x16x32_bf16(pa1, vb1, O[ds], 0, 0, 0);
    }
    __builtin_amdgcn_s_setprio(0);

    // ONE barrier per tile (dbuf: writes target buf[cur^1], last read at t-1)
    if (t + 1 < NT) {
      *(frag*)((char*)&Kt[cur ^ 1][0] + srow * 128 + kswz) = k0;
      *(frag*)((char*)&Vt[cur ^ 1][0] + srow * 128 + kswz) = v0;
      __syncthreads();
    }
  }

  if (SEG > 1) {
    size_t base = (size_t)(b * SEG + seg) * N_ + n0 + wave * 16;
    if (lq == 0) {       // lanes 0..15 hold q = l16 exactly
      ml[(base + l16) * 2]     = m_l;
      ml[(base + l16) * 2 + 1] = l_l;
    }
#pragma unroll
    for (int r = 0; r < 4; ++r)
#pragma unroll
      for (int ds = 0; ds < 4; ++ds)
        Opart[(base + lq * 4 + r) * 64 + ds * 16 + l16] = f2bf(O[ds][r]);
  } else {
    float inv[4];
#pragma unroll
    for (int r = 0; r < 4; ++r) inv[r] = 1.f / __shfl(l_l, 20 * lq + r, 64);
#pragma unroll
    for (int ds = 0; ds < 4; ++ds)
#pragma unroll
      for (int r = 0; r < 4; ++r)
        z[((size_t)b * N_ + n0 + wave * 16 + lq * 4 + r) * 128 + ds * 16 + l16] = O[ds][r] * inv[r];
  }
}

// combine SEG partials into z[ch 0..63] + fold per-block channel max -> mppA
template <int SEG>
__global__ __launch_bounds__(256) void combine_kernel(const unsigned short* __restrict__ Opart,
                                                      const float* __restrict__ ml,
                                                      float* __restrict__ z,
                                                      float* __restrict__ mppA) {
  __shared__ float zsm[64][65];
  int b = blockIdx.y, tid = threadIdx.x;
  int nr = tid >> 2;
  int n = blockIdx.x * 64 + nr;
  int dq = (tid & 3) * 16;
  float mv[SEG], lv[SEG], M = -1e30f;
#pragma unroll
  for (int s = 0; s < SEG; ++s) {
    size_t r = (size_t)(b * SEG + s) * N_ + n;
    mv[s] = ml[r * 2];
    lv[s] = ml[r * 2 + 1];
    M = fmaxf(M, mv[s]);
  }
  float acc[16];
#pragma unroll
  for (int j = 0; j < 16; ++j) acc[j] = 0.f;
  float l = 0.f;
#pragma unroll
  for (int s = 0; s < SEG; ++s) {
    float w = __expf(mv[s] - M);
    l += w * lv[s];
    const unsigned short* op = Opart + ((size_t)(b * SEG + s) * N_ + n) * 64 + dq;
    frag p0 = *(const frag*)(op);
    frag p1 = *(const frag*)(op + 8);
#pragma unroll
    for (int j = 0; j < 8; ++j) {
      acc[j]     += w * bf2f((unsigned short)p0[j]);
      acc[8 + j] += w * bf2f((unsigned short)p1[j]);
    }
  }
  float inv = 1.f / l;
  float* zp = z + ((size_t)b * N_ + n) * 128 + dq;
#pragma unroll
  for (int k = 0; k < 4; ++k) {
    f4 res = (f4){acc[4 * k] * inv, acc[4 * k + 1] * inv,
                  acc[4 * k + 2] * inv, acc[4 * k + 3] * inv};
    *(f4*)(zp + k * 4) = res;
    zsm[nr][dq + 4 * k]     = res.x;
    zsm[nr][dq + 4 * k + 1] = res.y;
    zsm[nr][dq + 4 * k + 2] = res.z;
    zsm[nr][dq + 4 * k + 3] = res.w;
  }
  __syncthreads();
  if (tid < 64) {
    float mx = -1e30f;
    for (int nn = 0; nn < 64; ++nn) mx = fmaxf(mx, zsm[nn][tid]);
    mppA[((size_t)b * 64 + blockIdx.x) * 64 + tid] = mx;
  }
}

// SEG=1 fallback: per-block channel max of z[ch 0..63]
__global__ __launch_bounds__(256) void mpA_kernel(const float* __restrict__ z,
                                                  float* __restrict__ mppA) {
  __shared__ float red[4][64];
  int b = blockIdx.y, n0 = blockIdx.x * 64, tid = threadIdx.x;
  int e = tid & 63, g = tid >> 6;
  float mx = -1e30f;
#pragma unroll
  for (int k = 0; k < 16; ++k)
    mx = fmaxf(mx, z[((size_t)b * N_ + n0 + g + 4 * k) * 128 + e]);
  red[g][e] = mx;
  __syncthreads();
  if (tid < 64)
    mppA[((size_t)b * 64 + blockIdx.x) * 64 + tid] =
        fmaxf(fmaxf(red[0][tid], red[1][tid]), fmaxf(red[2][tid], red[3][tid]));
}

// ---------------------------------------------------------------------------
// y2 via MFMA: z[b][n][64+c] = sum_e s2bf[c][e]*a1t[n][e]; per-block channel
// max -> mppB [B][128][64]. Grid (128, 4): 32 n per block.
// ---------------------------------------------------------------------------
__global__ __launch_bounds__(256) void y2_kernel(const unsigned short* __restrict__ s2bf,
                                                 const unsigned short* __restrict__ a1t,
                                                 float* __restrict__ z,
                                                 float* __restrict__ mppB) {
  __shared__ f4 red[4][4][16];   // [wave][lq][l16]
  int b = blockIdx.y, n0 = blockIdx.x * 32, tid = threadIdx.x;
  int wave = tid >> 6, lane = tid & 63, l16 = lane & 15, lq = lane >> 4;
  const unsigned short* s2r = s2bf + (size_t)b * 4096 + (16 * wave + l16) * 64;
  frag sa0 = *(const frag*)(s2r + lq * 8);
  frag sa1 = *(const frag*)(s2r + 32 + lq * 8);
  f4 mx = (f4){-1e30f, -1e30f, -1e30f, -1e30f};
#pragma unroll
  for (int j = 0; j < 2; ++j) {
    const unsigned short* bp = a1t + ((size_t)b * N_ + n0 + 16 * j + l16) * 64;
    frag b0 = *(const frag*)(bp + lq * 8);
    frag b1 = *(const frag*)(bp + 32 + lq * 8);
    f32x4 acc = (f32x4){0.f, 0.f, 0.f, 0.f};
    acc = __builtin_amdgcn_mfma_f32_16x16x32_bf16(sa0, b0, acc, 0, 0, 0);
    acc = __builtin_amdgcn_mfma_f32_16x16x32_bf16(sa1, b1, acc, 0, 0, 0);
    *(f4*)(z + ((size_t)b * N_ + n0 + 16 * j + l16) * 128 + 64 + 16 * wave + 4 * lq) = acc;
#pragma unroll
    for (int r = 0; r < 4; ++r) mx[r] = fmaxf(mx[r], acc[r]);
  }
  red[wave][lq][l16] = mx;
  __syncthreads();
  if (tid < 64) {
    int w = tid >> 4, q = (tid >> 2) & 3, r = tid & 3;
    float m = -1e30f;
#pragma unroll
    for (int l = 0; l < 16; ++l) m = fmaxf(m, red[w][q][l][r]);
    mppB[((size_t)b * 128 + blockIdx.x) * 64 + 16 * w + 4 * q + r] = m;
  }
}

// ---------------------------------------------------------------------------
// ca2: full channel attention, one block per batch.
// mppA [B][64][64]; mppB [B][128][64].
// ---------------------------------------------------------------------------
__global__ __launch_bounds__(256) void ca2_kernel(const float* __restrict__ mppA,
                                                  const float* __restrict__ mppB,
                                                  const float* __restrict__ fc1,
                                                  const float* __restrict__ fc2,
                                                  float* __restrict__ vbuf) {
  __shared__ f4 red4[256];
  __shared__ float mpl[128];
  __shared__ float red2[8][33];
  __shared__ float hl[8];
  int b = blockIdx.x, t = threadIdx.x;
  {
    const f4* src = (const f4*)(mppA + (size_t)b * 64 * 64);
    f4 m = src[t];
    m = max4(m, src[t + 256]);
    m = max4(m, src[t + 512]);
    m = max4(m, src[t + 768]);
    red4[t] = m;
  }
  __syncthreads();
  if (t < 16) {
    f4 m = red4[t];
#pragma unroll
    for (int j = 1; j < 16; ++j) m = max4(m, red4[t + 16 * j]);
    *(f4*)&mpl[t * 4] = m;
  }
  __syncthreads();
  {
    const f4* src = (const f4*)(mppB + (size_t)b * 128 * 64);
    f4 m = src[t];
#pragma unroll
    for (int k = 1; k < 8; ++k) m = max4(m, src[t + 256 * k]);
    red4[t] = m;
  }
  __syncthreads();
  if (t < 16) {
    f4 m = red4[t];
#pragma unroll
    for (int j = 1; j < 16; ++j) m = max4(m, red4[t + 16 * j]);
    *(f4*)&mpl[64 + t * 4] = m;
  }
  __syncthreads();
  {
    int r = t >> 5, j = t & 31;
    const f4 mv = *(const f4*)&mpl[j * 4];
    const f4 wv = *(const f4*)(fc1 + r * 128 + j * 4);
    red2[r][j] = mv.x * wv.x + mv.y * wv.y + mv.z * wv.z + mv.w * wv.w;
  }
  __syncthreads();
  if (t < 8) {
    float s = 0.f;
#pragma unroll
    for (int j = 0; j < 32; ++j) s += red2[t][j];
    hl[t] = fmaxf(s, 0.f);
  }
  __syncthreads();
  if (t < 128) {
    float s = 0.f;
    const float* f2r = fc2 + t * 8;
#pragma unroll
    for (int r = 0; r < 8; ++r) s += hl[r] * f2r[r];
    vbuf[b * 128 + t] = 1.f + 1.f / (1.f + __expf(-s));
  }
}

// ---------------------------------------------------------------------------
// final 1x1 conv via MFMA, 32-n tiles (grid 128 x B = 2 blocks/CU):
// out[b][o][n] = sum_e zv[n][e]*cw[o][e] + conv_b[o]
// ---------------------------------------------------------------------------
__global__ __launch_bounds__(256) void conv_kernel(const float* __restrict__ z,
                                                   const float* __restrict__ vbuf,
                                                   const float* __restrict__ conv_w,
                                                   const float* __restrict__ conv_b,
                                                   float* __restrict__ out) {
  __shared__ unsigned short zv[32 * 128];   // [n][e] bf16, row-XOR-swizzled (8 KB)
  int b = blockIdx.y, n0 = blockIdx.x * 32, tid = threadIdx.x;
  int wave = tid >> 6, lane = tid & 63, l16 = lane & 15, lq = lane >> 4;
  {  // stage zv: 4 f4 per thread; vq loop-invariant (e4 = tid&31)
    int e4 = tid & 31;
    f4 vq = *(const f4*)(vbuf + b * 128 + e4 * 4);
#pragma unroll
    for (int k = 0; k < 4; ++k) {
      int row = (tid >> 5) + 8 * k;
      f4 zq = *(const f4*)(z + ((size_t)(b * N_) + n0 + row) * 128 + e4 * 4);
      zq *= vq;
      uint2 w;
      w.x = pkbf(zq.x, zq.y);
      w.y = pkbf(zq.z, zq.w);
      *(uint2*)((char*)zv + row * 256 + ((e4 * 8) ^ ((row & 7) << 4))) = w;
    }
  }
  const float* cwr = conv_w + (size_t)(16 * wave + l16) * 128 + lq * 8;
  frag aw[4];
#pragma unroll
  for (int ks = 0; ks < 4; ++ks)
    aw[ks] = pk8(*(const f4*)(cwr + ks * 32), *(const f4*)(cwr + ks * 32 + 4));
  __syncthreads();
  f32x4 acc[2];
#pragma unroll
  for (int ng = 0; ng < 2; ++ng) acc[ng] = (f32x4){0.f, 0.f, 0.f, 0.f};
#pragma unroll
  for (int ng = 0; ng < 2; ++ng) {
    int n = ng * 16 + l16;
    int swz = (n & 7) << 4;
#pragma unroll
    for (int ks = 0; ks < 4; ++ks) {
      frag bz = *(const frag*)((char*)zv + n * 256 + ((ks * 64 + lq * 16) ^ swz));
      acc[ng] = __builtin_amdgcn_mfma_f32_16x16x32_bf16(aw[ks], bz, acc[ng], 0, 0, 0);
    }
  }
#pragma unroll
  for (int r = 0; r < 4; ++r) {
    int o = 16 * wave + 4 * lq + r;
    float bias = conv_b[o];
#pragma unroll
    for (int ng = 0; ng < 2; ++ng)
      out[((size_t)(b * C_ + o)) * N_ + n0 + ng * 16 + l16] = acc[ng][r] + bias;
  }
}

// ---------------------------------------------------------------------------
extern "C" void kernel_launch(void* const* d_in, const int* in_sizes, int n_in,
                              void* d_out, int out_size, void* d_ws, size_t ws_size,
                              hipStream_t stream) {
  const float* x1      = (const float*)d_in[0];
  const float* x2      = (const float*)d_in[1];
  const float* weight  = (const float*)d_in[2];
  const float* weight2 = (const float*)d_in[3];
  const float* fc1     = (const float*)d_in[4];
  const float* fc2     = (const float*)d_in[5];
  const float* conv_w  = (const float*)d_in[6];
  const float* conv_b  = (const float*)d_in[7];
  float* out = (float*)d_out;

  // workspace layout
  char* ws = (char*)d_ws;
  unsigned short* a1t = (unsigned short*)(ws + 0);          // 2 MB bf16 [B][N][C]
  unsigned short* a2t = (unsigned short*)(ws + 2097152);    // 2 MB bf16 [B][N][C]
  // post-attn aliases of the a2t region:
  float* mppA = (float*)(ws + 2097152);                     // 64 KB [B][64][64]
  float* mppB = (float*)(ws + 2162688);                     // 128 KB [B][128][64]
  unsigned short* s2bf = (unsigned short*)(ws + 2293760);   // 32 KB bf16 [B][C][C]
  unsigned short* vT  = (unsigned short*)(ws + 4194304);    // 2 MB bf16 [B][C][N]
  float* z    = (float*)(ws + 6291456);                     // 8 MB fp32 [B][N][2C]
  float* cxp  = (float*)(ws + 6291456);                     // 4 MB, aliases z (dead before attn)
  float* cx   = (float*)(ws + 14680064);                    // 64 KB [B][64*64] (cxT: [d][c])
  float* vbuf = (float*)(ws + 14745600);                    // 2 KB  [B][128]
  unsigned short* Opart = (unsigned short*)(ws + 14764544); // 8/16.8 MB bf16 [B][SEG][N][64]
  float* ml4  = (float*)(ws + 23153152);                    // 512 KB (SEG=4 ml)
  float* ml8  = (float*)(ws + 31541760);                    // 1 MB   (SEG=8 ml)
  const bool seg8 = ws_size >= 32590336ull;
  const bool seg4 = ws_size >= 23677440ull;

  prep_kernel<<<dim3(64, 4), 256, 0, stream>>>(x1, x2, a1t, a2t, cxp);
  support_mm_kernel<<<dim3(128, 4), 256, 0, stream>>>(weight, a2t, vT);
  cxred_kernel<<<dim3(64), 256, 0, stream>>>(cxp, cx);
  if (seg8) {
    attn_kernel<8><<<dim3(32, 4, 8), 512, 0, stream>>>(a1t, a2t, vT, z, Opart, ml8);
    combine_kernel<8><<<dim3(64, 4), 256, 0, stream>>>(Opart, ml8, z, mppA);
  } else if (seg4) {
    attn_kernel<4><<<dim3(32, 4, 4), 512, 0, stream>>>(a1t, a2t, vT, z, Opart, ml4);
    combine_kernel<4><<<dim3(64, 4), 256, 0, stream>>>(Opart, ml4, z, mppA);
  } else {
    attn_kernel<1><<<dim3(32, 4), 512, 0, stream>>>(a1t, a2t, vT, z, nullptr, nullptr);
    mpA_kernel<<<dim3(64, 4), 256, 0, stream>>>(z, mppA);
  }
  s2bf_kernel<<<dim3(4), 256, 0, stream>>>(cx, weight2, s2bf);      // a2t dead now
  y2_kernel<<<dim3(128, 4), 256, 0, stream>>>(s2bf, a1t, z, mppB);
  ca2_kernel<<<dim3(4), 256, 0, stream>>>(mppA, mppB, fc1, fc2, vbuf);
  conv_kernel<<<dim3(128, 4), 256, 0, stream>>>(z, vbuf, conv_w, conv_b, out);
}

// Round 16
// 71.355 us; speedup vs baseline: 1.0617x; 1.0617x over previous
//
#include <hip/hip_runtime.h>
#include <hip/hip_bf16.h>
#include <math.h>

// Problem constants (B,C,H,W = 4,64,64,64)
#define B_   4
#define C_   64
#define N_   4096   // H*W
#define C2_  128

using frag  = __attribute__((ext_vector_type(8))) short;  // 8 bf16 (4 VGPRs)
using f32x4 = __attribute__((ext_vector_type(4))) float;
using f4    = __attribute__((ext_vector_type(4))) float;

__device__ __forceinline__ unsigned short f2bf(float f) {
  unsigned int u = __float_as_uint(f);
  u += 0x7fffu + ((u >> 16) & 1u);   // RNE
  return (unsigned short)(u >> 16);
}
__device__ __forceinline__ float bf2f(unsigned short h) {
  return __uint_as_float(((unsigned int)h) << 16);
}
// pack 2 floats -> 2 bf16 in one u32 (compiler fuses to v_cvt_pk_bf16_f32)
__device__ __forceinline__ unsigned int pkbf(float a, float b) {
  __hip_bfloat16 ha = __float2bfloat16(a), hb = __float2bfloat16(b);
  unsigned short ua, ub;
  __builtin_memcpy(&ua, &ha, 2);
  __builtin_memcpy(&ub, &hb, 2);
  return (unsigned int)ua | ((unsigned int)ub << 16);
}
// 8 fp32 -> bf16 A/B fragment
__device__ __forceinline__ frag pk8(f4 lo, f4 hi) {
  frag f;
  unsigned int* u = (unsigned int*)&f;
  u[0] = pkbf(lo.x, lo.y);
  u[1] = pkbf(lo.z, lo.w);
  u[2] = pkbf(hi.x, hi.y);
  u[3] = pkbf(hi.z, hi.w);
  return f;
}
__device__ __forceinline__ f4 max4(f4 a, f4 b) {
  return (f4){fmaxf(a.x, b.x), fmaxf(a.y, b.y), fmaxf(a.z, b.z), fmaxf(a.w, b.w)};
}

// ---------------------------------------------------------------------------
// prep + cx + support fused: stage x1,x2 64-n tiles + W once; emit
//   a1t,a2t bf16 [N][C]; cxp partial (MFMA from LDS tiles);
//   vT[d][n] = sum_c W[c][d]*x2[c][n] (MFMA: A=W^T from LDS-W, B=x2 tile).
// LDS ~50 KB, grid (64, B).
// ---------------------------------------------------------------------------
__global__ __launch_bounds__(256) void prep_kernel(const float* __restrict__ x1,
                                                   const float* __restrict__ x2,
                                                   const float* __restrict__ weight,
                                                   unsigned short* __restrict__ a1t,
                                                   unsigned short* __restrict__ a2t,
                                                   unsigned short* __restrict__ vT,
                                                   float* __restrict__ cxp) {
  __shared__ float tA[64 * 65];   // x2 [c][n], padded
  __shared__ float tB[64 * 65];   // x1
  __shared__ float Wl[64 * 65];   // W  [c][d], padded
  int b = blockIdx.y, n0 = blockIdx.x * 64, tid = threadIdx.x;
  int wave = tid >> 6, lane = tid & 63, l16 = lane & 15, lq = lane >> 4;
  {
    int n = tid & 63, cq = tid >> 6;
#pragma unroll
    for (int k = 0; k < 16; ++k) {
      int c = cq + 4 * k;
      tA[c * 65 + n] = x2[((size_t)(b * C_ + c)) * N_ + n0 + n];   // coalesced
      tB[c * 65 + n] = x1[((size_t)(b * C_ + c)) * N_ + n0 + n];
      Wl[c * 65 + n] = weight[c * 64 + n];                          // [c][d]
    }
  }
  __syncthreads();
  {  // transpose-out (stride-65 conflict-free reads, coalesced writes)
    int c = tid & 63, nq = tid >> 6;
#pragma unroll
    for (int k = 0; k < 16; ++k) {
      int n2 = nq + 4 * k;
      a2t[((size_t)b * N_ + n0 + n2) * C_ + c] = f2bf(tA[c * 65 + n2]);
      a1t[((size_t)b * N_ + n0 + n2) * C_ + c] = f2bf(tB[c * 65 + n2]);
    }
  }
  {  // cx partial via MFMA: cxp[d*64+c] = sum_n x2[d][n]*x1[c][n]
    int dd = 16 * wave + l16;
    frag afr[2];
#pragma unroll
    for (int ks = 0; ks < 2; ++ks) {
      float w0[8];
#pragma unroll
      for (int j = 0; j < 8; ++j) w0[j] = tA[dd * 65 + ks * 32 + lq * 8 + j];
      afr[ks] = pk8((f4){w0[0], w0[1], w0[2], w0[3]}, (f4){w0[4], w0[5], w0[6], w0[7]});
    }
    f32x4 acc[4];
#pragma unroll
    for (int cg = 0; cg < 4; ++cg) acc[cg] = (f32x4){0.f, 0.f, 0.f, 0.f};
#pragma unroll
    for (int cg = 0; cg < 4; ++cg) {
      int cc = cg * 16 + l16;
#pragma unroll
      for (int ks = 0; ks < 2; ++ks) {
        float w0[8];
#pragma unroll
        for (int j = 0; j < 8; ++j) w0[j] = tB[cc * 65 + ks * 32 + lq * 8 + j];
        frag bfr = pk8((f4){w0[0], w0[1], w0[2], w0[3]}, (f4){w0[4], w0[5], w0[6], w0[7]});
        acc[cg] = __builtin_amdgcn_mfma_f32_16x16x32_bf16(afr[ks], bfr, acc[cg], 0, 0, 0);
      }
    }
    float* op = cxp + ((size_t)(b * 64 + blockIdx.x)) * 4096;
#pragma unroll
    for (int cg = 0; cg < 4; ++cg)
#pragma unroll
      for (int r = 0; r < 4; ++r)
        op[(16 * wave + 4 * lq + r) * 64 + cg * 16 + l16] = acc[cg][r];
  }
  {  // vT via MFMA: vT[d][n] = sum_c W[c][d] * x2[c][n]
    int dd = 16 * wave + l16;
    frag aw[2];
#pragma unroll
    for (int ks = 0; ks < 2; ++ks) {
      float wv[8];
#pragma unroll
      for (int j = 0; j < 8; ++j) wv[j] = Wl[(ks * 32 + lq * 8 + j) * 65 + dd];  // 2-way free
      aw[ks] = pk8((f4){wv[0], wv[1], wv[2], wv[3]}, (f4){wv[4], wv[5], wv[6], wv[7]});
    }
#pragma unroll
    for (int ng = 0; ng < 4; ++ng) {
      int nn = ng * 16 + l16;
      f32x4 acc = (f32x4){0.f, 0.f, 0.f, 0.f};
#pragma unroll
      for (int ks = 0; ks < 2; ++ks) {
        float bx[8];
#pragma unroll
        for (int j = 0; j < 8; ++j) bx[j] = tA[(ks * 32 + lq * 8 + j) * 65 + nn];  // cf banks
        frag bf = pk8((f4){bx[0], bx[1], bx[2], bx[3]}, (f4){bx[4], bx[5], bx[6], bx[7]});
        acc = __builtin_amdgcn_mfma_f32_16x16x32_bf16(aw[ks], bf, acc, 0, 0, 0);
      }
      // D[row = d = 16w+4lq+r][col = n = n0+nn]; stores coalesce over l16
#pragma unroll
      for (int r = 0; r < 4; ++r)
        vT[((size_t)(b * C_) + 16 * wave + 4 * lq + r) * N_ + n0 + nn] = f2bf(acc[r]);
    }
  }
}

// cx reduce: cx[b][idx] = sum_seg cxp[b][seg][idx]   (cxT layout [d][c])
__global__ __launch_bounds__(256) void cxred_kernel(const float* __restrict__ cxp,
                                                    float* __restrict__ cx) {
  int idx = blockIdx.x * 256 + threadIdx.x;   // 0..16383
  int b = idx >> 12, r = idx & 4095;
  const float* p = cxp + (size_t)b * 64 * 4096 + r;
  float s = 0.f;
#pragma unroll 8
  for (int sg = 0; sg < 64; ++sg) s += p[(size_t)sg * 4096];
  cx[idx] = s;
}

// ---------------------------------------------------------------------------
// s2bf: s2[b][c][e] = sum_d cxT[d][c] * w2[d][e]  -> bf16 row-major [c][e]
// NOTE: s2bf buffer aliases a2t -> must run AFTER attn.
// ---------------------------------------------------------------------------
__global__ __launch_bounds__(256) void s2bf_kernel(const float* __restrict__ cx,
                                                   const float* __restrict__ w2,
                                                   unsigned short* __restrict__ s2bf) {
  __shared__ float cxl[4096];
  __shared__ float w2l[4096];
  int b = blockIdx.x, tid = threadIdx.x;
#pragma unroll
  for (int k = 0; k < 16; ++k) {
    int lin = tid + 256 * k;
    cxl[lin] = cx[(size_t)b * 4096 + lin];
    w2l[lin] = w2[lin];
  }
  __syncthreads();
  int c = tid & 63, eg = tid >> 6;
  float acc[16];
#pragma unroll
  for (int i = 0; i < 16; ++i) acc[i] = 0.f;
  for (int d = 0; d < 64; ++d) {
    float a = cxl[d * 64 + c];                               // per-lane cf
#pragma unroll
    for (int i = 0; i < 16; ++i) acc[i] += a * w2l[d * 64 + eg * 16 + i];  // broadcast
  }
  unsigned short* op = s2bf + (size_t)b * 4096 + c * 64 + eg * 16;
#pragma unroll
  for (int i = 0; i < 8; ++i)
    *(unsigned int*)(op + 2 * i) = pkbf(acc[2 * i], acc[2 * i + 1]);
}

// ---------------------------------------------------------------------------
// Flash attention, 8-wave blocks (QBLK=128, 16 q/wave), KV-split SEG=4,
// swapped QK^T, defer-max, KV tile 64, register dbuf staging, one barrier
// per tile. (r14 kernel, unchanged.)
// ---------------------------------------------------------------------------
template <int SEG>
__global__ __launch_bounds__(512) void attn_kernel(const unsigned short* __restrict__ a1t,
                                                   const unsigned short* __restrict__ a2t,
                                                   const unsigned short* __restrict__ vT,
                                                   float* __restrict__ z,
                                                   unsigned short* __restrict__ Opart,
                                                   float* __restrict__ ml) {
  __shared__ unsigned short Kt[2][64 * 64];    // [m][c] bf16, row-XOR-swizzled
  __shared__ unsigned short Vt[2][64 * 64];    // [d][m] bf16, row-XOR-swizzled
  __shared__ uint2 Pl[8][16 * 16];             // per-wave P [q][kv] bf16, swizzled

  const int b = blockIdx.y, n0 = blockIdx.x * 128, tid = threadIdx.x;
  const int seg = (SEG > 1) ? blockIdx.z : 0;
  const int wave = tid >> 6, lane = tid & 63;
  const int l16 = lane & 15, lq = lane >> 4;
  const int NT = N_ / SEG / 64;
  const int mbase = seg * (N_ / SEG);

  const unsigned short* qbase = a1t + ((size_t)b * N_ + n0 + wave * 16 + l16) * C_;
  frag qa0 = *(const frag*)(qbase + lq * 8);
  frag qa1 = *(const frag*)(qbase + 32 + lq * 8);

  f32x4 O[4];
#pragma unroll
  for (int i = 0; i < 4; ++i) O[i] = (f32x4){0.f, 0.f, 0.f, 0.f};
  float m_l = -1e30f, l_l = 0.f;   // running max/sum for q = l16 (replicated x4)

  const unsigned short* a2b = a2t + (size_t)b * N_ * C_;
  const unsigned short* vTb = vT + (size_t)b * C_ * N_;
  char* Pw = (char*)&Pl[wave][0];
  const int swzP = (l16 & 7) << 4;

  // staging: 512 threads x 1 K-frag + 1 V-frag per tile
  const int srow = tid >> 3, scb = tid & 7;
  const int kswz = (scb * 16) ^ ((srow & 7) << 4);

  // prologue: stage tile 0
  frag k0 = *(const frag*)(a2b + (size_t)(mbase + srow) * C_ + scb * 8);
  frag v0 = *(const frag*)(vTb + (size_t)srow * N_ + mbase + scb * 8);
  *(frag*)((char*)&Kt[0][0] + srow * 128 + kswz) = k0;
  *(frag*)((char*)&Vt[0][0] + srow * 128 + kswz) = v0;
  __syncthreads();

  int cur = 0;
  for (int t = 0; t < NT; ++t, cur ^= 1) {
    // T14 issue-early: next tile's global loads in flight during compute
    if (t + 1 < NT) {
      int mn = mbase + (t + 1) * 64;
      k0 = *(const frag*)(a2b + (size_t)(mn + srow) * C_ + scb * 8);
      v0 = *(const frag*)(vTb + (size_t)srow * N_ + mn + scb * 8);
    }

    // S^T = K Q^T (swapped): lane holds S[kv=16ms+4lq+r][q=l16]
    f32x4 S[4];
    __builtin_amdgcn_s_setprio(1);
#pragma unroll
    for (int ms = 0; ms < 4; ++ms) {
      int m = ms * 16 + l16;
      int swz = (m & 7) << 4;
      frag kb0 = *(const frag*)((char*)&Kt[cur][0] + m * 128 + ((lq * 16) ^ swz));
      frag kb1 = *(const frag*)((char*)&Kt[cur][0] + m * 128 + ((64 + lq * 16) ^ swz));
      f32x4 acc = (f32x4){0.f, 0.f, 0.f, 0.f};
      acc = __builtin_amdgcn_mfma_f32_16x16x32_bf16(kb0, qa0, acc, 0, 0, 0);
      acc = __builtin_amdgcn_mfma_f32_16x16x32_bf16(kb1, qa1, acc, 0, 0, 0);
      S[ms] = acc;
    }
    __builtin_amdgcn_s_setprio(0);

    // lane-local row max (16 values) + 2-shuffle cross-lq reduce
    float mx0 = fmaxf(fmaxf(S[0][0], S[0][1]), fmaxf(S[0][2], S[0][3]));
    float mx1 = fmaxf(fmaxf(S[1][0], S[1][1]), fmaxf(S[1][2], S[1][3]));
    float mx2 = fmaxf(fmaxf(S[2][0], S[2][1]), fmaxf(S[2][2], S[2][3]));
    float mx3 = fmaxf(fmaxf(S[3][0], S[3][1]), fmaxf(S[3][2], S[3][3]));
    float mx = fmaxf(fmaxf(mx0, mx1), fmaxf(mx2, mx3));
    mx = fmaxf(mx, __shfl_xor(mx, 16, 64));
    mx = fmaxf(mx, __shfl_xor(mx, 32, 64));

    // defer-max: rescale only if some row grew by > 8
    if (!__all(mx <= m_l + 8.f)) {
      float mn = fmaxf(m_l, mx);
      float sc = __expf(m_l - mn);
      m_l = mn;
      l_l *= sc;
      float scb_[4];
#pragma unroll
      for (int r = 0; r < 4; ++r) scb_[r] = __shfl(sc, 20 * lq + r, 64);  // sc for O-row 4lq+r
#pragma unroll
      for (int ds = 0; ds < 4; ++ds)
#pragma unroll
        for (int r = 0; r < 4; ++r) O[ds][r] *= scb_[r];
    }

    // P = exp(S - m), lane-local row sum + 2 shuffles
    float p[16];
    float rs = 0.f;
#pragma unroll
    for (int ms = 0; ms < 4; ++ms)
#pragma unroll
      for (int r = 0; r < 4; ++r) {
        float e = __expf(S[ms][r] - m_l);
        p[ms * 4 + r] = e;
        rs += e;
      }
    rs += __shfl_xor(rs, 16, 64);
    rs += __shfl_xor(rs, 32, 64);
    l_l += rs;

    // P -> per-wave LDS: 4x ds_write_b64 (packed bf16), [q][kv] swizzled
#pragma unroll
    for (int ms = 0; ms < 4; ++ms) {
      uint2 w;
      w.x = pkbf(p[ms * 4 + 0], p[ms * 4 + 1]);
      w.y = pkbf(p[ms * 4 + 2], p[ms * 4 + 3]);
      *(uint2*)(Pw + l16 * 128 + ((32 * ms + 8 * lq) ^ swzP)) = w;
    }
    asm volatile("s_waitcnt lgkmcnt(0)" ::: "memory");
    __builtin_amdgcn_sched_barrier(0);  // rule 18: keep reads below the wait

    // O += P V
    frag pa0 = *(const frag*)(Pw + l16 * 128 + ((lq * 16) ^ swzP));
    frag pa1 = *(const frag*)(Pw + l16 * 128 + ((64 + lq * 16) ^ swzP));
    __builtin_amdgcn_s_setprio(1);
#pragma unroll
    for (int ds = 0; ds < 4; ++ds) {
      int d = ds * 16 + l16;
      int swz = (d & 7) << 4;
      frag vb0 = *(const frag*)((char*)&Vt[cur][0] + d * 128 + ((lq * 16) ^ swz));
      frag vb1 = *(const frag*)((char*)&Vt[cur][0] + d * 128 + ((64 + lq * 16) ^ swz));
      O[ds] = __builtin_amdgcn_mfma_f32_16x16x32_bf16(pa0, vb0, O[ds], 0, 0, 0);
      O[ds] = __builtin_amdgcn_mfma_f32_16x16x32_bf16(pa1, vb1, O[ds], 0, 0, 0);
    }
    __builtin_amdgcn_s_setprio(0);

    // ONE barrier per tile (dbuf: writes target buf[cur^1], last read at t-1)
    if (t + 1 < NT) {
      *(frag*)((char*)&Kt[cur ^ 1][0] + srow * 128 + kswz) = k0;
      *(frag*)((char*)&Vt[cur ^ 1][0] + srow * 128 + kswz) = v0;
      __syncthreads();
    }
  }

  if (SEG > 1) {
    size_t base = (size_t)(b * SEG + seg) * N_ + n0 + wave * 16;
    if (lq == 0) {       // lanes 0..15 hold q = l16 exactly
      ml[(base + l16) * 2]     = m_l;
      ml[(base + l16) * 2 + 1] = l_l;
    }
#pragma unroll
    for (int r = 0; r < 4; ++r)
#pragma unroll
      for (int ds = 0; ds < 4; ++ds)
        Opart[(base + lq * 4 + r) * 64 + ds * 16 + l16] = f2bf(O[ds][r]);
  } else {
    float inv[4];
#pragma unroll
    for (int r = 0; r < 4; ++r) inv[r] = 1.f / __shfl(l_l, 20 * lq + r, 64);
#pragma unroll
    for (int ds = 0; ds < 4; ++ds)
#pragma unroll
      for (int r = 0; r < 4; ++r)
        z[((size_t)b * N_ + n0 + wave * 16 + lq * 4 + r) * 128 + ds * 16 + l16] = O[ds][r] * inv[r];
  }
}

// combine SEG partials into z[ch 0..63] + fold per-block channel max -> mppA
template <int SEG>
__global__ __launch_bounds__(256) void combine_kernel(const unsigned short* __restrict__ Opart,
                                                      const float* __restrict__ ml,
                                                      float* __restrict__ z,
                                                      float* __restrict__ mppA) {
  __shared__ float zsm[64][65];
  int b = blockIdx.y, tid = threadIdx.x;
  int nr = tid >> 2;
  int n = blockIdx.x * 64 + nr;
  int dq = (tid & 3) * 16;
  float mv[SEG], lv[SEG], M = -1e30f;
#pragma unroll
  for (int s = 0; s < SEG; ++s) {
    size_t r = (size_t)(b * SEG + s) * N_ + n;
    mv[s] = ml[r * 2];
    lv[s] = ml[r * 2 + 1];
    M = fmaxf(M, mv[s]);
  }
  float acc[16];
#pragma unroll
  for (int j = 0; j < 16; ++j) acc[j] = 0.f;
  float l = 0.f;
#pragma unroll
  for (int s = 0; s < SEG; ++s) {
    float w = __expf(mv[s] - M);
    l += w * lv[s];
    const unsigned short* op = Opart + ((size_t)(b * SEG + s) * N_ + n) * 64 + dq;
    frag p0 = *(const frag*)(op);
    frag p1 = *(const frag*)(op + 8);
#pragma unroll
    for (int j = 0; j < 8; ++j) {
      acc[j]     += w * bf2f((unsigned short)p0[j]);
      acc[8 + j] += w * bf2f((unsigned short)p1[j]);
    }
  }
  float inv = 1.f / l;
  float* zp = z + ((size_t)b * N_ + n) * 128 + dq;
#pragma unroll
  for (int k = 0; k < 4; ++k) {
    f4 res = (f4){acc[4 * k] * inv, acc[4 * k + 1] * inv,
                  acc[4 * k + 2] * inv, acc[4 * k + 3] * inv};
    *(f4*)(zp + k * 4) = res;
    zsm[nr][dq + 4 * k]     = res.x;
    zsm[nr][dq + 4 * k + 1] = res.y;
    zsm[nr][dq + 4 * k + 2] = res.z;
    zsm[nr][dq + 4 * k + 3] = res.w;
  }
  __syncthreads();
  if (tid < 64) {
    float mx = -1e30f;
    for (int nn = 0; nn < 64; ++nn) mx = fmaxf(mx, zsm[nn][tid]);
    mppA[((size_t)b * 64 + blockIdx.x) * 64 + tid] = mx;
  }
}

// SEG=1 fallback: per-block channel max of z[ch 0..63]
__global__ __launch_bounds__(256) void mpA_kernel(const float* __restrict__ z,
                                                  float* __restrict__ mppA) {
  __shared__ float red[4][64];
  int b = blockIdx.y, n0 = blockIdx.x * 64, tid = threadIdx.x;
  int e = tid & 63, g = tid >> 6;
  float mx = -1e30f;
#pragma unroll
  for (int k = 0; k < 16; ++k)
    mx = fmaxf(mx, z[((size_t)b * N_ + n0 + g + 4 * k) * 128 + e]);
  red[g][e] = mx;
  __syncthreads();
  if (tid < 64)
    mppA[((size_t)b * 64 + blockIdx.x) * 64 + tid] =
        fmaxf(fmaxf(red[0][tid], red[1][tid]), fmaxf(red[2][tid], red[3][tid]));
}

// ---------------------------------------------------------------------------
// y2 via MFMA: z[b][n][64+c] = sum_e s2bf[c][e]*a1t[n][e]; per-block channel
// max -> mppB [B][128][64]. Grid (128, 4): 32 n per block.
// ---------------------------------------------------------------------------
__global__ __launch_bounds__(256) void y2_kernel(const unsigned short* __restrict__ s2bf,
                                                 const unsigned short* __restrict__ a1t,
                                                 float* __restrict__ z,
                                                 float* __restrict__ mppB) {
  __shared__ f4 red[4][4][16];   // [wave][lq][l16]
  int b = blockIdx.y, n0 = blockIdx.x * 32, tid = threadIdx.x;
  int wave = tid >> 6, lane = tid & 63, l16 = lane & 15, lq = lane >> 4;
  const unsigned short* s2r = s2bf + (size_t)b * 4096 + (16 * wave + l16) * 64;
  frag sa0 = *(const frag*)(s2r + lq * 8);
  frag sa1 = *(const frag*)(s2r + 32 + lq * 8);
  f4 mx = (f4){-1e30f, -1e30f, -1e30f, -1e30f};
#pragma unroll
  for (int j = 0; j < 2; ++j) {
    const unsigned short* bp = a1t + ((size_t)b * N_ + n0 + 16 * j + l16) * 64;
    frag b0 = *(const frag*)(bp + lq * 8);
    frag b1 = *(const frag*)(bp + 32 + lq * 8);
    f32x4 acc = (f32x4){0.f, 0.f, 0.f, 0.f};
    acc = __builtin_amdgcn_mfma_f32_16x16x32_bf16(sa0, b0, acc, 0, 0, 0);
    acc = __builtin_amdgcn_mfma_f32_16x16x32_bf16(sa1, b1, acc, 0, 0, 0);
    *(f4*)(z + ((size_t)b * N_ + n0 + 16 * j + l16) * 128 + 64 + 16 * wave + 4 * lq) = acc;
#pragma unroll
    for (int r = 0; r < 4; ++r) mx[r] = fmaxf(mx[r], acc[r]);
  }
  red[wave][lq][l16] = mx;
  __syncthreads();
  if (tid < 64) {
    int w = tid >> 4, q = (tid >> 2) & 3, r = tid & 3;
    float m = -1e30f;
#pragma unroll
    for (int l = 0; l < 16; ++l) m = fmaxf(m, red[w][q][l][r]);
    mppB[((size_t)b * 128 + blockIdx.x) * 64 + 16 * w + 4 * q + r] = m;
  }
}

// ---------------------------------------------------------------------------
// ca2: full channel attention, one block per batch.
// mppA [B][64][64]; mppB [B][128][64].
// ---------------------------------------------------------------------------
__global__ __launch_bounds__(256) void ca2_kernel(const float* __restrict__ mppA,
                                                  const float* __restrict__ mppB,
                                                  const float* __restrict__ fc1,
                                                  const float* __restrict__ fc2,
                                                  float* __restrict__ vbuf) {
  __shared__ f4 red4[256];
  __shared__ float mpl[128];
  __shared__ float red2[8][33];
  __shared__ float hl[8];
  int b = blockIdx.x, t = threadIdx.x;
  {
    const f4* src = (const f4*)(mppA + (size_t)b * 64 * 64);
    f4 m = src[t];
    m = max4(m, src[t + 256]);
    m = max4(m, src[t + 512]);
    m = max4(m, src[t + 768]);
    red4[t] = m;
  }
  __syncthreads();
  if (t < 16) {
    f4 m = red4[t];
#pragma unroll
    for (int j = 1; j < 16; ++j) m = max4(m, red4[t + 16 * j]);
    *(f4*)&mpl[t * 4] = m;
  }
  __syncthreads();
  {
    const f4* src = (const f4*)(mppB + (size_t)b * 128 * 64);
    f4 m = src[t];
#pragma unroll
    for (int k = 1; k < 8; ++k) m = max4(m, src[t + 256 * k]);
    red4[t] = m;
  }
  __syncthreads();
  if (t < 16) {
    f4 m = red4[t];
#pragma unroll
    for (int j = 1; j < 16; ++j) m = max4(m, red4[t + 16 * j]);
    *(f4*)&mpl[64 + t * 4] = m;
  }
  __syncthreads();
  {
    int r = t >> 5, j = t & 31;
    const f4 mv = *(const f4*)&mpl[j * 4];
    const f4 wv = *(const f4*)(fc1 + r * 128 + j * 4);
    red2[r][j] = mv.x * wv.x + mv.y * wv.y + mv.z * wv.z + mv.w * wv.w;
  }
  __syncthreads();
  if (t < 8) {
    float s = 0.f;
#pragma unroll
    for (int j = 0; j < 32; ++j) s += red2[t][j];
    hl[t] = fmaxf(s, 0.f);
  }
  __syncthreads();
  if (t < 128) {
    float s = 0.f;
    const float* f2r = fc2 + t * 8;
#pragma unroll
    for (int r = 0; r < 8; ++r) s += hl[r] * f2r[r];
    vbuf[b * 128 + t] = 1.f + 1.f / (1.f + __expf(-s));
  }
}

// ---------------------------------------------------------------------------
// final 1x1 conv via MFMA, 32-n tiles (grid 128 x B = 2 blocks/CU):
// out[b][o][n] = sum_e zv[n][e]*cw[o][e] + conv_b[o]
// ---------------------------------------------------------------------------
__global__ __launch_bounds__(256) void conv_kernel(const float* __restrict__ z,
                                                   const float* __restrict__ vbuf,
                                                   const float* __restrict__ conv_w,
                                                   const float* __restrict__ conv_b,
                                                   float* __restrict__ out) {
  __shared__ unsigned short zv[32 * 128];   // [n][e] bf16, row-XOR-swizzled (8 KB)
  int b = blockIdx.y, n0 = blockIdx.x * 32, tid = threadIdx.x;
  int wave = tid >> 6, lane = tid & 63, l16 = lane & 15, lq = lane >> 4;
  {  // stage zv: 4 f4 per thread; vq loop-invariant (e4 = tid&31)
    int e4 = tid & 31;
    f4 vq = *(const f4*)(vbuf + b * 128 + e4 * 4);
#pragma unroll
    for (int k = 0; k < 4; ++k) {
      int row = (tid >> 5) + 8 * k;
      f4 zq = *(const f4*)(z + ((size_t)(b * N_) + n0 + row) * 128 + e4 * 4);
      zq *= vq;
      uint2 w;
      w.x = pkbf(zq.x, zq.y);
      w.y = pkbf(zq.z, zq.w);
      *(uint2*)((char*)zv + row * 256 + ((e4 * 8) ^ ((row & 7) << 4))) = w;
    }
  }
  const float* cwr = conv_w + (size_t)(16 * wave + l16) * 128 + lq * 8;
  frag aw[4];
#pragma unroll
  for (int ks = 0; ks < 4; ++ks)
    aw[ks] = pk8(*(const f4*)(cwr + ks * 32), *(const f4*)(cwr + ks * 32 + 4));
  __syncthreads();
  f32x4 acc[2];
#pragma unroll
  for (int ng = 0; ng < 2; ++ng) acc[ng] = (f32x4){0.f, 0.f, 0.f, 0.f};
#pragma unroll
  for (int ng = 0; ng < 2; ++ng) {
    int n = ng * 16 + l16;
    int swz = (n & 7) << 4;
#pragma unroll
    for (int ks = 0; ks < 4; ++ks) {
      frag bz = *(const frag*)((char*)zv + n * 256 + ((ks * 64 + lq * 16) ^ swz));
      acc[ng] = __builtin_amdgcn_mfma_f32_16x16x32_bf16(aw[ks], bz, acc[ng], 0, 0, 0);
    }
  }
#pragma unroll
  for (int r = 0; r < 4; ++r) {
    int o = 16 * wave + 4 * lq + r;
    float bias = conv_b[o];
#pragma unroll
    for (int ng = 0; ng < 2; ++ng)
      out[((size_t)(b * C_ + o)) * N_ + n0 + ng * 16 + l16] = acc[ng][r] + bias;
  }
}

// ---------------------------------------------------------------------------
extern "C" void kernel_launch(void* const* d_in, const int* in_sizes, int n_in,
                              void* d_out, int out_size, void* d_ws, size_t ws_size,
                              hipStream_t stream) {
  const float* x1      = (const float*)d_in[0];
  const float* x2      = (const float*)d_in[1];
  const float* weight  = (const float*)d_in[2];
  const float* weight2 = (const float*)d_in[3];
  const float* fc1     = (const float*)d_in[4];
  const float* fc2     = (const float*)d_in[5];
  const float* conv_w  = (const float*)d_in[6];
  const float* conv_b  = (const float*)d_in[7];
  float* out = (float*)d_out;

  // workspace layout
  char* ws = (char*)d_ws;
  unsigned short* a1t = (unsigned short*)(ws + 0);          // 2 MB bf16 [B][N][C]
  unsigned short* a2t = (unsigned short*)(ws + 2097152);    // 2 MB bf16 [B][N][C]
  // post-attn aliases of the a2t region:
  float* mppA = (float*)(ws + 2097152);                     // 64 KB [B][64][64]
  float* mppB = (float*)(ws + 2162688);                     // 128 KB [B][128][64]
  unsigned short* s2bf = (unsigned short*)(ws + 2293760);   // 32 KB bf16 [B][C][C]
  unsigned short* vT  = (unsigned short*)(ws + 4194304);    // 2 MB bf16 [B][C][N]
  float* z    = (float*)(ws + 6291456);                     // 8 MB fp32 [B][N][2C]
  float* cxp  = (float*)(ws + 6291456);                     // 4 MB, aliases z (dead before attn)
  float* cx   = (float*)(ws + 14680064);                    // 64 KB [B][64*64] (cxT: [d][c])
  float* vbuf = (float*)(ws + 14745600);                    // 2 KB  [B][128]
  unsigned short* Opart = (unsigned short*)(ws + 14764544); // 8 MB bf16 [B][4][N][64]
  float* ml   = (float*)(ws + 23153152);                    // 512 KB [B][4][N][2]
  const bool seg4 = ws_size >= 23677440ull;

  prep_kernel<<<dim3(64, 4), 256, 0, stream>>>(x1, x2, weight, a1t, a2t, vT, cxp);
  cxred_kernel<<<dim3(64), 256, 0, stream>>>(cxp, cx);
  if (seg4) {
    attn_kernel<4><<<dim3(32, 4, 4), 512, 0, stream>>>(a1t, a2t, vT, z, Opart, ml);
    combine_kernel<4><<<dim3(64, 4), 256, 0, stream>>>(Opart, ml, z, mppA);
  } else {
    attn_kernel<1><<<dim3(32, 4), 512, 0, stream>>>(a1t, a2t, vT, z, nullptr, nullptr);
    mpA_kernel<<<dim3(64, 4), 256, 0, stream>>>(z, mppA);
  }
  s2bf_kernel<<<dim3(4), 256, 0, stream>>>(cx, weight2, s2bf);      // a2t dead now
  y2_kernel<<<dim3(128, 4), 256, 0, stream>>>(s2bf, a1t, z, mppB);
  ca2_kernel<<<dim3(4), 256, 0, stream>>>(mppA, mppB, fc1, fc2, vbuf);
  conv_kernel<<<dim3(128, 4), 256, 0, stream>>>(z, vbuf, conv_w, conv_b, out);
}

// Round 17
// 69.547 us; speedup vs baseline: 1.0894x; 1.0260x over previous
//
#include <hip/hip_runtime.h>
#include <hip/hip_bf16.h>
#include <math.h>

// Problem constants (B,C,H,W = 4,64,64,64)
#define B_   4
#define C_   64
#define N_   4096   // H*W
#define C2_  128

using frag  = __attribute__((ext_vector_type(8))) short;  // 8 bf16 (4 VGPRs)
using f32x4 = __attribute__((ext_vector_type(4))) float;
using f4    = __attribute__((ext_vector_type(4))) float;

__device__ __forceinline__ unsigned short f2bf(float f) {
  unsigned int u = __float_as_uint(f);
  u += 0x7fffu + ((u >> 16) & 1u);   // RNE
  return (unsigned short)(u >> 16);
}
__device__ __forceinline__ float bf2f(unsigned short h) {
  return __uint_as_float(((unsigned int)h) << 16);
}
// pack 2 floats -> 2 bf16 in one u32 (compiler fuses to v_cvt_pk_bf16_f32)
__device__ __forceinline__ unsigned int pkbf(float a, float b) {
  __hip_bfloat16 ha = __float2bfloat16(a), hb = __float2bfloat16(b);
  unsigned short ua, ub;
  __builtin_memcpy(&ua, &ha, 2);
  __builtin_memcpy(&ub, &hb, 2);
  return (unsigned int)ua | ((unsigned int)ub << 16);
}
// 8 fp32 -> bf16 A/B fragment
__device__ __forceinline__ frag pk8(f4 lo, f4 hi) {
  frag f;
  unsigned int* u = (unsigned int*)&f;
  u[0] = pkbf(lo.x, lo.y);
  u[1] = pkbf(lo.z, lo.w);
  u[2] = pkbf(hi.x, hi.y);
  u[3] = pkbf(hi.z, hi.w);
  return f;
}
__device__ __forceinline__ f4 max4(f4 a, f4 b) {
  return (f4){fmaxf(a.x, b.x), fmaxf(a.y, b.y), fmaxf(a.z, b.z), fmaxf(a.w, b.w)};
}

// ---------------------------------------------------------------------------
// prep + cx + support fused (r16, unchanged): stage x1,x2 64-n tiles + W once;
// emit a1t,a2t bf16 [N][C]; cxp partial (MFMA); vT (MFMA).
// ---------------------------------------------------------------------------
__global__ __launch_bounds__(256) void prep_kernel(const float* __restrict__ x1,
                                                   const float* __restrict__ x2,
                                                   const float* __restrict__ weight,
                                                   unsigned short* __restrict__ a1t,
                                                   unsigned short* __restrict__ a2t,
                                                   unsigned short* __restrict__ vT,
                                                   float* __restrict__ cxp) {
  __shared__ float tA[64 * 65];   // x2 [c][n], padded
  __shared__ float tB[64 * 65];   // x1
  __shared__ float Wl[64 * 65];   // W  [c][d], padded
  int b = blockIdx.y, n0 = blockIdx.x * 64, tid = threadIdx.x;
  int wave = tid >> 6, lane = tid & 63, l16 = lane & 15, lq = lane >> 4;
  {
    int n = tid & 63, cq = tid >> 6;
#pragma unroll
    for (int k = 0; k < 16; ++k) {
      int c = cq + 4 * k;
      tA[c * 65 + n] = x2[((size_t)(b * C_ + c)) * N_ + n0 + n];   // coalesced
      tB[c * 65 + n] = x1[((size_t)(b * C_ + c)) * N_ + n0 + n];
      Wl[c * 65 + n] = weight[c * 64 + n];                          // [c][d]
    }
  }
  __syncthreads();
  {  // transpose-out (stride-65 conflict-free reads, coalesced writes)
    int c = tid & 63, nq = tid >> 6;
#pragma unroll
    for (int k = 0; k < 16; ++k) {
      int n2 = nq + 4 * k;
      a2t[((size_t)b * N_ + n0 + n2) * C_ + c] = f2bf(tA[c * 65 + n2]);
      a1t[((size_t)b * N_ + n0 + n2) * C_ + c] = f2bf(tB[c * 65 + n2]);
    }
  }
  {  // cx partial via MFMA: cxp[d*64+c] = sum_n x2[d][n]*x1[c][n]
    int dd = 16 * wave + l16;
    frag afr[2];
#pragma unroll
    for (int ks = 0; ks < 2; ++ks) {
      float w0[8];
#pragma unroll
      for (int j = 0; j < 8; ++j) w0[j] = tA[dd * 65 + ks * 32 + lq * 8 + j];
      afr[ks] = pk8((f4){w0[0], w0[1], w0[2], w0[3]}, (f4){w0[4], w0[5], w0[6], w0[7]});
    }
    f32x4 acc[4];
#pragma unroll
    for (int cg = 0; cg < 4; ++cg) acc[cg] = (f32x4){0.f, 0.f, 0.f, 0.f};
#pragma unroll
    for (int cg = 0; cg < 4; ++cg) {
      int cc = cg * 16 + l16;
#pragma unroll
      for (int ks = 0; ks < 2; ++ks) {
        float w0[8];
#pragma unroll
        for (int j = 0; j < 8; ++j) w0[j] = tB[cc * 65 + ks * 32 + lq * 8 + j];
        frag bfr = pk8((f4){w0[0], w0[1], w0[2], w0[3]}, (f4){w0[4], w0[5], w0[6], w0[7]});
        acc[cg] = __builtin_amdgcn_mfma_f32_16x16x32_bf16(afr[ks], bfr, acc[cg], 0, 0, 0);
      }
    }
    float* op = cxp + ((size_t)(b * 64 + blockIdx.x)) * 4096;
#pragma unroll
    for (int cg = 0; cg < 4; ++cg)
#pragma unroll
      for (int r = 0; r < 4; ++r)
        op[(16 * wave + 4 * lq + r) * 64 + cg * 16 + l16] = acc[cg][r];
  }
  {  // vT via MFMA: vT[d][n] = sum_c W[c][d] * x2[c][n]
    int dd = 16 * wave + l16;
    frag aw[2];
#pragma unroll
    for (int ks = 0; ks < 2; ++ks) {
      float wv[8];
#pragma unroll
      for (int j = 0; j < 8; ++j) wv[j] = Wl[(ks * 32 + lq * 8 + j) * 65 + dd];  // 2-way free
      aw[ks] = pk8((f4){wv[0], wv[1], wv[2], wv[3]}, (f4){wv[4], wv[5], wv[6], wv[7]});
    }
#pragma unroll
    for (int ng = 0; ng < 4; ++ng) {
      int nn = ng * 16 + l16;
      f32x4 acc = (f32x4){0.f, 0.f, 0.f, 0.f};
#pragma unroll
      for (int ks = 0; ks < 2; ++ks) {
        float bx[8];
#pragma unroll
        for (int j = 0; j < 8; ++j) bx[j] = tA[(ks * 32 + lq * 8 + j) * 65 + nn];  // cf banks
        frag bf = pk8((f4){bx[0], bx[1], bx[2], bx[3]}, (f4){bx[4], bx[5], bx[6], bx[7]});
        acc = __builtin_amdgcn_mfma_f32_16x16x32_bf16(aw[ks], bf, acc, 0, 0, 0);
      }
#pragma unroll
      for (int r = 0; r < 4; ++r)
        vT[((size_t)(b * C_) + 16 * wave + 4 * lq + r) * N_ + n0 + nn] = f2bf(acc[r]);
    }
  }
}

// cx reduce: cx[b][idx] = sum_seg cxp[b][seg][idx]   (cxT layout [d][c])
__global__ __launch_bounds__(256) void cxred_kernel(const float* __restrict__ cxp,
                                                    float* __restrict__ cx) {
  int idx = blockIdx.x * 256 + threadIdx.x;   // 0..16383
  int b = idx >> 12, r = idx & 4095;
  const float* p = cxp + (size_t)b * 64 * 4096 + r;
  float s = 0.f;
#pragma unroll 8
  for (int sg = 0; sg < 64; ++sg) s += p[(size_t)sg * 4096];
  cx[idx] = s;
}

// ---------------------------------------------------------------------------
// s2bf: s2[b][c][e] = sum_d cxT[d][c] * w2[d][e]  -> bf16 row-major [c][e]
// NOTE: s2bf buffer aliases a2t -> must run AFTER attn.
// ---------------------------------------------------------------------------
__global__ __launch_bounds__(256) void s2bf_kernel(const float* __restrict__ cx,
                                                   const float* __restrict__ w2,
                                                   unsigned short* __restrict__ s2bf) {
  __shared__ float cxl[4096];
  __shared__ float w2l[4096];
  int b = blockIdx.x, tid = threadIdx.x;
#pragma unroll
  for (int k = 0; k < 16; ++k) {
    int lin = tid + 256 * k;
    cxl[lin] = cx[(size_t)b * 4096 + lin];
    w2l[lin] = w2[lin];
  }
  __syncthreads();
  int c = tid & 63, eg = tid >> 6;
  float acc[16];
#pragma unroll
  for (int i = 0; i < 16; ++i) acc[i] = 0.f;
  for (int d = 0; d < 64; ++d) {
    float a = cxl[d * 64 + c];                               // per-lane cf
#pragma unroll
    for (int i = 0; i < 16; ++i) acc[i] += a * w2l[d * 64 + eg * 16 + i];  // broadcast
  }
  unsigned short* op = s2bf + (size_t)b * 4096 + c * 64 + eg * 16;
#pragma unroll
  for (int i = 0; i < 8; ++i)
    *(unsigned int*)(op + 2 * i) = pkbf(acc[2 * i], acc[2 * i + 1]);
}

// ---------------------------------------------------------------------------
// Flash attention, 8-wave blocks (QBLK=128, 16 q/wave), KV-split SEG=4,
// swapped QK^T, defer-max, KV tile 64, register dbuf staging, one barrier
// per tile. (r14/r16 kernel, unchanged.)
// ---------------------------------------------------------------------------
template <int SEG>
__global__ __launch_bounds__(512) void attn_kernel(const unsigned short* __restrict__ a1t,
                                                   const unsigned short* __restrict__ a2t,
                                                   const unsigned short* __restrict__ vT,
                                                   float* __restrict__ z,
                                                   unsigned short* __restrict__ Opart,
                                                   float* __restrict__ ml) {
  __shared__ unsigned short Kt[2][64 * 64];    // [m][c] bf16, row-XOR-swizzled
  __shared__ unsigned short Vt[2][64 * 64];    // [d][m] bf16, row-XOR-swizzled
  __shared__ uint2 Pl[8][16 * 16];             // per-wave P [q][kv] bf16, swizzled

  const int b = blockIdx.y, n0 = blockIdx.x * 128, tid = threadIdx.x;
  const int seg = (SEG > 1) ? blockIdx.z : 0;
  const int wave = tid >> 6, lane = tid & 63;
  const int l16 = lane & 15, lq = lane >> 4;
  const int NT = N_ / SEG / 64;
  const int mbase = seg * (N_ / SEG);

  const unsigned short* qbase = a1t + ((size_t)b * N_ + n0 + wave * 16 + l16) * C_;
  frag qa0 = *(const frag*)(qbase + lq * 8);
  frag qa1 = *(const frag*)(qbase + 32 + lq * 8);

  f32x4 O[4];
#pragma unroll
  for (int i = 0; i < 4; ++i) O[i] = (f32x4){0.f, 0.f, 0.f, 0.f};
  float m_l = -1e30f, l_l = 0.f;   // running max/sum for q = l16 (replicated x4)

  const unsigned short* a2b = a2t + (size_t)b * N_ * C_;
  const unsigned short* vTb = vT + (size_t)b * C_ * N_;
  char* Pw = (char*)&Pl[wave][0];
  const int swzP = (l16 & 7) << 4;

  // staging: 512 threads x 1 K-frag + 1 V-frag per tile
  const int srow = tid >> 3, scb = tid & 7;
  const int kswz = (scb * 16) ^ ((srow & 7) << 4);

  // prologue: stage tile 0
  frag k0 = *(const frag*)(a2b + (size_t)(mbase + srow) * C_ + scb * 8);
  frag v0 = *(const frag*)(vTb + (size_t)srow * N_ + mbase + scb * 8);
  *(frag*)((char*)&Kt[0][0] + srow * 128 + kswz) = k0;
  *(frag*)((char*)&Vt[0][0] + srow * 128 + kswz) = v0;
  __syncthreads();

  int cur = 0;
  for (int t = 0; t < NT; ++t, cur ^= 1) {
    // T14 issue-early: next tile's global loads in flight during compute
    if (t + 1 < NT) {
      int mn = mbase + (t + 1) * 64;
      k0 = *(const frag*)(a2b + (size_t)(mn + srow) * C_ + scb * 8);
      v0 = *(const frag*)(vTb + (size_t)srow * N_ + mn + scb * 8);
    }

    // S^T = K Q^T (swapped): lane holds S[kv=16ms+4lq+r][q=l16]
    f32x4 S[4];
    __builtin_amdgcn_s_setprio(1);
#pragma unroll
    for (int ms = 0; ms < 4; ++ms) {
      int m = ms * 16 + l16;
      int swz = (m & 7) << 4;
      frag kb0 = *(const frag*)((char*)&Kt[cur][0] + m * 128 + ((lq * 16) ^ swz));
      frag kb1 = *(const frag*)((char*)&Kt[cur][0] + m * 128 + ((64 + lq * 16) ^ swz));
      f32x4 acc = (f32x4){0.f, 0.f, 0.f, 0.f};
      acc = __builtin_amdgcn_mfma_f32_16x16x32_bf16(kb0, qa0, acc, 0, 0, 0);
      acc = __builtin_amdgcn_mfma_f32_16x16x32_bf16(kb1, qa1, acc, 0, 0, 0);
      S[ms] = acc;
    }
    __builtin_amdgcn_s_setprio(0);

    // lane-local row max (16 values) + 2-shuffle cross-lq reduce
    float mx0 = fmaxf(fmaxf(S[0][0], S[0][1]), fmaxf(S[0][2], S[0][3]));
    float mx1 = fmaxf(fmaxf(S[1][0], S[1][1]), fmaxf(S[1][2], S[1][3]));
    float mx2 = fmaxf(fmaxf(S[2][0], S[2][1]), fmaxf(S[2][2], S[2][3]));
    float mx3 = fmaxf(fmaxf(S[3][0], S[3][1]), fmaxf(S[3][2], S[3][3]));
    float mx = fmaxf(fmaxf(mx0, mx1), fmaxf(mx2, mx3));
    mx = fmaxf(mx, __shfl_xor(mx, 16, 64));
    mx = fmaxf(mx, __shfl_xor(mx, 32, 64));

    // defer-max: rescale only if some row grew by > 8
    if (!__all(mx <= m_l + 8.f)) {
      float mn = fmaxf(m_l, mx);
      float sc = __expf(m_l - mn);
      m_l = mn;
      l_l *= sc;
      float scb_[4];
#pragma unroll
      for (int r = 0; r < 4; ++r) scb_[r] = __shfl(sc, 20 * lq + r, 64);  // sc for O-row 4lq+r
#pragma unroll
      for (int ds = 0; ds < 4; ++ds)
#pragma unroll
        for (int r = 0; r < 4; ++r) O[ds][r] *= scb_[r];
    }

    // P = exp(S - m), lane-local row sum + 2 shuffles
    float p[16];
    float rs = 0.f;
#pragma unroll
    for (int ms = 0; ms < 4; ++ms)
#pragma unroll
      for (int r = 0; r < 4; ++r) {
        float e = __expf(S[ms][r] - m_l);
        p[ms * 4 + r] = e;
        rs += e;
      }
    rs += __shfl_xor(rs, 16, 64);
    rs += __shfl_xor(rs, 32, 64);
    l_l += rs;

    // P -> per-wave LDS: 4x ds_write_b64 (packed bf16), [q][kv] swizzled
#pragma unroll
    for (int ms = 0; ms < 4; ++ms) {
      uint2 w;
      w.x = pkbf(p[ms * 4 + 0], p[ms * 4 + 1]);
      w.y = pkbf(p[ms * 4 + 2], p[ms * 4 + 3]);
      *(uint2*)(Pw + l16 * 128 + ((32 * ms + 8 * lq) ^ swzP)) = w;
    }
    asm volatile("s_waitcnt lgkmcnt(0)" ::: "memory");
    __builtin_amdgcn_sched_barrier(0);  // rule 18: keep reads below the wait

    // O += P V
    frag pa0 = *(const frag*)(Pw + l16 * 128 + ((lq * 16) ^ swzP));
    frag pa1 = *(const frag*)(Pw + l16 * 128 + ((64 + lq * 16) ^ swzP));
    __builtin_amdgcn_s_setprio(1);
#pragma unroll
    for (int ds = 0; ds < 4; ++ds) {
      int d = ds * 16 + l16;
      int swz = (d & 7) << 4;
      frag vb0 = *(const frag*)((char*)&Vt[cur][0] + d * 128 + ((lq * 16) ^ swz));
      frag vb1 = *(const frag*)((char*)&Vt[cur][0] + d * 128 + ((64 + lq * 16) ^ swz));
      O[ds] = __builtin_amdgcn_mfma_f32_16x16x32_bf16(pa0, vb0, O[ds], 0, 0, 0);
      O[ds] = __builtin_amdgcn_mfma_f32_16x16x32_bf16(pa1, vb1, O[ds], 0, 0, 0);
    }
    __builtin_amdgcn_s_setprio(0);

    // ONE barrier per tile (dbuf: writes target buf[cur^1], last read at t-1)
    if (t + 1 < NT) {
      *(frag*)((char*)&Kt[cur ^ 1][0] + srow * 128 + kswz) = k0;
      *(frag*)((char*)&Vt[cur ^ 1][0] + srow * 128 + kswz) = v0;
      __syncthreads();
    }
  }

  if (SEG > 1) {
    size_t base = (size_t)(b * SEG + seg) * N_ + n0 + wave * 16;
    if (lq == 0) {       // lanes 0..15 hold q = l16 exactly
      ml[(base + l16) * 2]     = m_l;
      ml[(base + l16) * 2 + 1] = l_l;
    }
#pragma unroll
    for (int r = 0; r < 4; ++r)
#pragma unroll
      for (int ds = 0; ds < 4; ++ds)
        Opart[(base + lq * 4 + r) * 64 + ds * 16 + l16] = f2bf(O[ds][r]);
  } else {
    float inv[4];
#pragma unroll
    for (int r = 0; r < 4; ++r) inv[r] = 1.f / __shfl(l_l, 20 * lq + r, 64);
#pragma unroll
    for (int ds = 0; ds < 4; ++ds)
#pragma unroll
      for (int r = 0; r < 4; ++r)
        z[((size_t)b * N_ + n0 + wave * 16 + lq * 4 + r) * 128 + ds * 16 + l16] = O[ds][r] * inv[r];
  }
}

// ---------------------------------------------------------------------------
// y2 phase (shared): 64 n per block, wave w owns c-strip 16w; writes z
// ch 64..127 + per-block channel max -> mppB [B][64][64].
// ---------------------------------------------------------------------------
__device__ __forceinline__ void y2_phase(const unsigned short* __restrict__ s2bf,
                                         const unsigned short* __restrict__ a1t,
                                         float* __restrict__ z,
                                         float* __restrict__ mppB,
                                         f4 (*red)[4][16],
                                         int b, int blkx, int tid) {
  int n0 = blkx * 64;
  int wave = tid >> 6, lane = tid & 63, l16 = lane & 15, lq = lane >> 4;
  const unsigned short* s2r = s2bf + (size_t)b * 4096 + (16 * wave + l16) * 64;
  frag sa0 = *(const frag*)(s2r + lq * 8);
  frag sa1 = *(const frag*)(s2r + 32 + lq * 8);
  f4 mx = (f4){-1e30f, -1e30f, -1e30f, -1e30f};
#pragma unroll
  for (int ng = 0; ng < 4; ++ng) {
    const unsigned short* bp = a1t + ((size_t)b * N_ + n0 + ng * 16 + l16) * 64;
    frag b0 = *(const frag*)(bp + lq * 8);
    frag b1 = *(const frag*)(bp + 32 + lq * 8);
    f32x4 acc = (f32x4){0.f, 0.f, 0.f, 0.f};
    acc = __builtin_amdgcn_mfma_f32_16x16x32_bf16(sa0, b0, acc, 0, 0, 0);
    acc = __builtin_amdgcn_mfma_f32_16x16x32_bf16(sa1, b1, acc, 0, 0, 0);
    *(f4*)(z + ((size_t)b * N_ + n0 + ng * 16 + l16) * 128 + 64 + 16 * wave + 4 * lq) = acc;
#pragma unroll
    for (int r = 0; r < 4; ++r) mx[r] = fmaxf(mx[r], acc[r]);
  }
  red[wave][lq][l16] = mx;
  __syncthreads();
  if (tid < 64) {
    int w = tid >> 4, q = (tid >> 2) & 3, r = tid & 3;
    float m = -1e30f;
#pragma unroll
    for (int l = 0; l < 16; ++l) m = fmaxf(m, red[w][q][l][r]);
    mppB[((size_t)b * 64 + blkx) * 64 + 16 * w + 4 * q + r] = m;
  }
}

// combine SEG partials -> z[ch 0..63] + mppA; then fused y2 -> z[ch 64..127] + mppB
template <int SEG>
__global__ __launch_bounds__(256) void combineY2_kernel(const unsigned short* __restrict__ Opart,
                                                        const float* __restrict__ ml,
                                                        const unsigned short* __restrict__ s2bf,
                                                        const unsigned short* __restrict__ a1t,
                                                        float* __restrict__ z,
                                                        float* __restrict__ mppA,
                                                        float* __restrict__ mppB) {
  __shared__ float zsm[64][65];
  __shared__ f4 red[4][4][16];
  int b = blockIdx.y, tid = threadIdx.x;
  int nr = tid >> 2;
  int n = blockIdx.x * 64 + nr;
  int dq = (tid & 3) * 16;
  float mv[SEG], lv[SEG], M = -1e30f;
#pragma unroll
  for (int s = 0; s < SEG; ++s) {
    size_t r = (size_t)(b * SEG + s) * N_ + n;
    mv[s] = ml[r * 2];
    lv[s] = ml[r * 2 + 1];
    M = fmaxf(M, mv[s]);
  }
  float acc[16];
#pragma unroll
  for (int j = 0; j < 16; ++j) acc[j] = 0.f;
  float l = 0.f;
#pragma unroll
  for (int s = 0; s < SEG; ++s) {
    float w = __expf(mv[s] - M);
    l += w * lv[s];
    const unsigned short* op = Opart + ((size_t)(b * SEG + s) * N_ + n) * 64 + dq;
    frag p0 = *(const frag*)(op);
    frag p1 = *(const frag*)(op + 8);
#pragma unroll
    for (int j = 0; j < 8; ++j) {
      acc[j]     += w * bf2f((unsigned short)p0[j]);
      acc[8 + j] += w * bf2f((unsigned short)p1[j]);
    }
  }
  float inv = 1.f / l;
  float* zp = z + ((size_t)b * N_ + n) * 128 + dq;
#pragma unroll
  for (int k = 0; k < 4; ++k) {
    f4 res = (f4){acc[4 * k] * inv, acc[4 * k + 1] * inv,
                  acc[4 * k + 2] * inv, acc[4 * k + 3] * inv};
    *(f4*)(zp + k * 4) = res;
    zsm[nr][dq + 4 * k]     = res.x;
    zsm[nr][dq + 4 * k + 1] = res.y;
    zsm[nr][dq + 4 * k + 2] = res.z;
    zsm[nr][dq + 4 * k + 3] = res.w;
  }
  __syncthreads();
  if (tid < 64) {
    float mx = -1e30f;
    for (int nn = 0; nn < 64; ++nn) mx = fmaxf(mx, zsm[nn][tid]);
    mppA[((size_t)b * 64 + blockIdx.x) * 64 + tid] = mx;
  }
  // fused y2 for the same 64 n-rows (has its own barrier inside)
  y2_phase(s2bf, a1t, z, mppB, red, b, blockIdx.x, tid);
}

// SEG=1 fallbacks
__global__ __launch_bounds__(256) void mpA_kernel(const float* __restrict__ z,
                                                  float* __restrict__ mppA) {
  __shared__ float red[4][64];
  int b = blockIdx.y, n0 = blockIdx.x * 64, tid = threadIdx.x;
  int e = tid & 63, g = tid >> 6;
  float mx = -1e30f;
#pragma unroll
  for (int k = 0; k < 16; ++k)
    mx = fmaxf(mx, z[((size_t)b * N_ + n0 + g + 4 * k) * 128 + e]);
  red[g][e] = mx;
  __syncthreads();
  if (tid < 64)
    mppA[((size_t)b * 64 + blockIdx.x) * 64 + tid] =
        fmaxf(fmaxf(red[0][tid], red[1][tid]), fmaxf(red[2][tid], red[3][tid]));
}

__global__ __launch_bounds__(256) void y2_kernel(const unsigned short* __restrict__ s2bf,
                                                 const unsigned short* __restrict__ a1t,
                                                 float* __restrict__ z,
                                                 float* __restrict__ mppB) {
  __shared__ f4 red[4][4][16];
  y2_phase(s2bf, a1t, z, mppB, red, blockIdx.y, blockIdx.x, threadIdx.x);
}

// ---------------------------------------------------------------------------
// ca2: full channel attention, one block per batch.
// mppA, mppB both [B][64][64].
// ---------------------------------------------------------------------------
__global__ __launch_bounds__(256) void ca2_kernel(const float* __restrict__ mppA,
                                                  const float* __restrict__ mppB,
                                                  const float* __restrict__ fc1,
                                                  const float* __restrict__ fc2,
                                                  float* __restrict__ vbuf) {
  __shared__ f4 red4[256];
  __shared__ float mpl[128];
  __shared__ float red2[8][33];
  __shared__ float hl[8];
  int b = blockIdx.x, t = threadIdx.x;
  {
    const f4* src = (const f4*)(mppA + (size_t)b * 64 * 64);
    f4 m = src[t];
    m = max4(m, src[t + 256]);
    m = max4(m, src[t + 512]);
    m = max4(m, src[t + 768]);
    red4[t] = m;
  }
  __syncthreads();
  if (t < 16) {
    f4 m = red4[t];
#pragma unroll
    for (int j = 1; j < 16; ++j) m = max4(m, red4[t + 16 * j]);
    *(f4*)&mpl[t * 4] = m;
  }
  __syncthreads();
  {
    const f4* src = (const f4*)(mppB + (size_t)b * 64 * 64);
    f4 m = src[t];
    m = max4(m, src[t + 256]);
    m = max4(m, src[t + 512]);
    m = max4(m, src[t + 768]);
    red4[t] = m;
  }
  __syncthreads();
  if (t < 16) {
    f4 m = red4[t];
#pragma unroll
    for (int j = 1; j < 16; ++j) m = max4(m, red4[t + 16 * j]);
    *(f4*)&mpl[64 + t * 4] = m;
  }
  __syncthreads();
  {
    int r = t >> 5, j = t & 31;
    const f4 mv = *(const f4*)&mpl[j * 4];
    const f4 wv = *(const f4*)(fc1 + r * 128 + j * 4);
    red2[r][j] = mv.x * wv.x + mv.y * wv.y + mv.z * wv.z + mv.w * wv.w;
  }
  __syncthreads();
  if (t < 8) {
    float s = 0.f;
#pragma unroll
    for (int j = 0; j < 32; ++j) s += red2[t][j];
    hl[t] = fmaxf(s, 0.f);
  }
  __syncthreads();
  if (t < 128) {
    float s = 0.f;
    const float* f2r = fc2 + t * 8;
#pragma unroll
    for (int r = 0; r < 8; ++r) s += hl[r] * f2r[r];
    vbuf[b * 128 + t] = 1.f + 1.f / (1.f + __expf(-s));
  }
}

// ---------------------------------------------------------------------------
// final 1x1 conv via MFMA, 32-n tiles (r16, unchanged)
// ---------------------------------------------------------------------------
__global__ __launch_bounds__(256) void conv_kernel(const float* __restrict__ z,
                                                   const float* __restrict__ vbuf,
                                                   const float* __restrict__ conv_w,
                                                   const float* __restrict__ conv_b,
                                                   float* __restrict__ out) {
  __shared__ unsigned short zv[32 * 128];   // [n][e] bf16, row-XOR-swizzled (8 KB)
  int b = blockIdx.y, n0 = blockIdx.x * 32, tid = threadIdx.x;
  int wave = tid >> 6, lane = tid & 63, l16 = lane & 15, lq = lane >> 4;
  {  // stage zv: 4 f4 per thread; vq loop-invariant (e4 = tid&31)
    int e4 = tid & 31;
    f4 vq = *(const f4*)(vbuf + b * 128 + e4 * 4);
#pragma unroll
    for (int k = 0; k < 4; ++k) {
      int row = (tid >> 5) + 8 * k;
      f4 zq = *(const f4*)(z + ((size_t)(b * N_) + n0 + row) * 128 + e4 * 4);
      zq *= vq;
      uint2 w;
      w.x = pkbf(zq.x, zq.y);
      w.y = pkbf(zq.z, zq.w);
      *(uint2*)((char*)zv + row * 256 + ((e4 * 8) ^ ((row & 7) << 4))) = w;
    }
  }
  const float* cwr = conv_w + (size_t)(16 * wave + l16) * 128 + lq * 8;
  frag aw[4];
#pragma unroll
  for (int ks = 0; ks < 4; ++ks)
    aw[ks] = pk8(*(const f4*)(cwr + ks * 32), *(const f4*)(cwr + ks * 32 + 4));
  __syncthreads();
  f32x4 acc[2];
#pragma unroll
  for (int ng = 0; ng < 2; ++ng) acc[ng] = (f32x4){0.f, 0.f, 0.f, 0.f};
#pragma unroll
  for (int ng = 0; ng < 2; ++ng) {
    int n = ng * 16 + l16;
    int swz = (n & 7) << 4;
#pragma unroll
    for (int ks = 0; ks < 4; ++ks) {
      frag bz = *(const frag*)((char*)zv + n * 256 + ((ks * 64 + lq * 16) ^ swz));
      acc[ng] = __builtin_amdgcn_mfma_f32_16x16x32_bf16(aw[ks], bz, acc[ng], 0, 0, 0);
    }
  }
#pragma unroll
  for (int r = 0; r < 4; ++r) {
    int o = 16 * wave + 4 * lq + r;
    float bias = conv_b[o];
#pragma unroll
    for (int ng = 0; ng < 2; ++ng)
      out[((size_t)(b * C_ + o)) * N_ + n0 + ng * 16 + l16] = acc[ng][r] + bias;
  }
}

// ---------------------------------------------------------------------------
extern "C" void kernel_launch(void* const* d_in, const int* in_sizes, int n_in,
                              void* d_out, int out_size, void* d_ws, size_t ws_size,
                              hipStream_t stream) {
  const float* x1      = (const float*)d_in[0];
  const float* x2      = (const float*)d_in[1];
  const float* weight  = (const float*)d_in[2];
  const float* weight2 = (const float*)d_in[3];
  const float* fc1     = (const float*)d_in[4];
  const float* fc2     = (const float*)d_in[5];
  const float* conv_w  = (const float*)d_in[6];
  const float* conv_b  = (const float*)d_in[7];
  float* out = (float*)d_out;

  // workspace layout
  char* ws = (char*)d_ws;
  unsigned short* a1t = (unsigned short*)(ws + 0);          // 2 MB bf16 [B][N][C]
  unsigned short* a2t = (unsigned short*)(ws + 2097152);    // 2 MB bf16 [B][N][C]
  // post-attn aliases of the a2t region:
  float* mppA = (float*)(ws + 2097152);                     // 64 KB [B][64][64]
  float* mppB = (float*)(ws + 2162688);                     // 64 KB [B][64][64]
  unsigned short* s2bf = (unsigned short*)(ws + 2293760);   // 32 KB bf16 [B][C][C]
  unsigned short* vT  = (unsigned short*)(ws + 4194304);    // 2 MB bf16 [B][C][N]
  float* z    = (float*)(ws + 6291456);                     // 8 MB fp32 [B][N][2C]
  float* cxp  = (float*)(ws + 6291456);                     // 4 MB, aliases z (dead before attn)
  float* cx   = (float*)(ws + 14680064);                    // 64 KB [B][64*64] (cxT: [d][c])
  float* vbuf = (float*)(ws + 14745600);                    // 2 KB  [B][128]
  unsigned short* Opart = (unsigned short*)(ws + 14764544); // 8 MB bf16 [B][4][N][64]
  float* ml   = (float*)(ws + 23153152);                    // 512 KB [B][4][N][2]
  const bool seg4 = ws_size >= 23677440ull;

  prep_kernel<<<dim3(64, 4), 256, 0, stream>>>(x1, x2, weight, a1t, a2t, vT, cxp);
  cxred_kernel<<<dim3(64), 256, 0, stream>>>(cxp, cx);
  if (seg4) {
    attn_kernel<4><<<dim3(32, 4, 4), 512, 0, stream>>>(a1t, a2t, vT, z, Opart, ml);
    s2bf_kernel<<<dim3(4), 256, 0, stream>>>(cx, weight2, s2bf);    // a2t dead now
    combineY2_kernel<4><<<dim3(64, 4), 256, 0, stream>>>(Opart, ml, s2bf, a1t, z, mppA, mppB);
  } else {
    attn_kernel<1><<<dim3(32, 4), 512, 0, stream>>>(a1t, a2t, vT, z, nullptr, nullptr);
    s2bf_kernel<<<dim3(4), 256, 0, stream>>>(cx, weight2, s2bf);
    mpA_kernel<<<dim3(64, 4), 256, 0, stream>>>(z, mppA);
    y2_kernel<<<dim3(64, 4), 256, 0, stream>>>(s2bf, a1t, z, mppB);
  }
  ca2_kernel<<<dim3(4), 256, 0, stream>>>(mppA, mppB, fc1, fc2, vbuf);
  conv_kernel<<<dim3(128, 4), 256, 0, stream>>>(z, vbuf, conv_w, conv_b, out);
}

// Round 18
// 69.483 us; speedup vs baseline: 1.0903x; 1.0009x over previous
//
#include <hip/hip_runtime.h>
#include <hip/hip_bf16.h>
#include <math.h>

// Problem constants (B,C,H,W = 4,64,64,64)
#define B_   4
#define C_   64
#define N_   4096   // H*W
#define C2_  128

using frag  = __attribute__((ext_vector_type(8))) short;  // 8 bf16 (4 VGPRs)
using f32x4 = __attribute__((ext_vector_type(4))) float;
using f4    = __attribute__((ext_vector_type(4))) float;

__device__ __forceinline__ unsigned short f2bf(float f) {
  unsigned int u = __float_as_uint(f);
  u += 0x7fffu + ((u >> 16) & 1u);   // RNE
  return (unsigned short)(u >> 16);
}
__device__ __forceinline__ float bf2f(unsigned short h) {
  return __uint_as_float(((unsigned int)h) << 16);
}
// pack 2 floats -> 2 bf16 in one u32 (compiler fuses to v_cvt_pk_bf16_f32)
__device__ __forceinline__ unsigned int pkbf(float a, float b) {
  __hip_bfloat16 ha = __float2bfloat16(a), hb = __float2bfloat16(b);
  unsigned short ua, ub;
  __builtin_memcpy(&ua, &ha, 2);
  __builtin_memcpy(&ub, &hb, 2);
  return (unsigned int)ua | ((unsigned int)ub << 16);
}
// 8 fp32 -> bf16 A/B fragment
__device__ __forceinline__ frag pk8(f4 lo, f4 hi) {
  frag f;
  unsigned int* u = (unsigned int*)&f;
  u[0] = pkbf(lo.x, lo.y);
  u[1] = pkbf(lo.z, lo.w);
  u[2] = pkbf(hi.x, hi.y);
  u[3] = pkbf(hi.z, hi.w);
  return f;
}
__device__ __forceinline__ f4 max4(f4 a, f4 b) {
  return (f4){fmaxf(a.x, b.x), fmaxf(a.y, b.y), fmaxf(a.z, b.z), fmaxf(a.w, b.w)};
}

// ---------------------------------------------------------------------------
// prep + cx + support fused (r16/r17, unchanged): stage x1,x2 64-n tiles + W;
// emit a1t,a2t bf16 [N][C]; cxp partial (MFMA); vT (MFMA).
// ---------------------------------------------------------------------------
__global__ __launch_bounds__(256) void prep_kernel(const float* __restrict__ x1,
                                                   const float* __restrict__ x2,
                                                   const float* __restrict__ weight,
                                                   unsigned short* __restrict__ a1t,
                                                   unsigned short* __restrict__ a2t,
                                                   unsigned short* __restrict__ vT,
                                                   float* __restrict__ cxp) {
  __shared__ float tA[64 * 65];   // x2 [c][n], padded
  __shared__ float tB[64 * 65];   // x1
  __shared__ float Wl[64 * 65];   // W  [c][d], padded
  int b = blockIdx.y, n0 = blockIdx.x * 64, tid = threadIdx.x;
  int wave = tid >> 6, lane = tid & 63, l16 = lane & 15, lq = lane >> 4;
  {
    int n = tid & 63, cq = tid >> 6;
#pragma unroll
    for (int k = 0; k < 16; ++k) {
      int c = cq + 4 * k;
      tA[c * 65 + n] = x2[((size_t)(b * C_ + c)) * N_ + n0 + n];   // coalesced
      tB[c * 65 + n] = x1[((size_t)(b * C_ + c)) * N_ + n0 + n];
      Wl[c * 65 + n] = weight[c * 64 + n];                          // [c][d]
    }
  }
  __syncthreads();
  {  // transpose-out (stride-65 conflict-free reads, coalesced writes)
    int c = tid & 63, nq = tid >> 6;
#pragma unroll
    for (int k = 0; k < 16; ++k) {
      int n2 = nq + 4 * k;
      a2t[((size_t)b * N_ + n0 + n2) * C_ + c] = f2bf(tA[c * 65 + n2]);
      a1t[((size_t)b * N_ + n0 + n2) * C_ + c] = f2bf(tB[c * 65 + n2]);
    }
  }
  {  // cx partial via MFMA: cxp[d*64+c] = sum_n x2[d][n]*x1[c][n]
    int dd = 16 * wave + l16;
    frag afr[2];
#pragma unroll
    for (int ks = 0; ks < 2; ++ks) {
      float w0[8];
#pragma unroll
      for (int j = 0; j < 8; ++j) w0[j] = tA[dd * 65 + ks * 32 + lq * 8 + j];
      afr[ks] = pk8((f4){w0[0], w0[1], w0[2], w0[3]}, (f4){w0[4], w0[5], w0[6], w0[7]});
    }
    f32x4 acc[4];
#pragma unroll
    for (int cg = 0; cg < 4; ++cg) acc[cg] = (f32x4){0.f, 0.f, 0.f, 0.f};
#pragma unroll
    for (int cg = 0; cg < 4; ++cg) {
      int cc = cg * 16 + l16;
#pragma unroll
      for (int ks = 0; ks < 2; ++ks) {
        float w0[8];
#pragma unroll
        for (int j = 0; j < 8; ++j) w0[j] = tB[cc * 65 + ks * 32 + lq * 8 + j];
        frag bfr = pk8((f4){w0[0], w0[1], w0[2], w0[3]}, (f4){w0[4], w0[5], w0[6], w0[7]});
        acc[cg] = __builtin_amdgcn_mfma_f32_16x16x32_bf16(afr[ks], bfr, acc[cg], 0, 0, 0);
      }
    }
    float* op = cxp + ((size_t)(b * 64 + blockIdx.x)) * 4096;
#pragma unroll
    for (int cg = 0; cg < 4; ++cg)
#pragma unroll
      for (int r = 0; r < 4; ++r)
        op[(16 * wave + 4 * lq + r) * 64 + cg * 16 + l16] = acc[cg][r];
  }
  {  // vT via MFMA: vT[d][n] = sum_c W[c][d] * x2[c][n]
    int dd = 16 * wave + l16;
    frag aw[2];
#pragma unroll
    for (int ks = 0; ks < 2; ++ks) {
      float wv[8];
#pragma unroll
      for (int j = 0; j < 8; ++j) wv[j] = Wl[(ks * 32 + lq * 8 + j) * 65 + dd];  // 2-way free
      aw[ks] = pk8((f4){wv[0], wv[1], wv[2], wv[3]}, (f4){wv[4], wv[5], wv[6], wv[7]});
    }
#pragma unroll
    for (int ng = 0; ng < 4; ++ng) {
      int nn = ng * 16 + l16;
      f32x4 acc = (f32x4){0.f, 0.f, 0.f, 0.f};
#pragma unroll
      for (int ks = 0; ks < 2; ++ks) {
        float bx[8];
#pragma unroll
        for (int j = 0; j < 8; ++j) bx[j] = tA[(ks * 32 + lq * 8 + j) * 65 + nn];  // cf banks
        frag bf = pk8((f4){bx[0], bx[1], bx[2], bx[3]}, (f4){bx[4], bx[5], bx[6], bx[7]});
        acc = __builtin_amdgcn_mfma_f32_16x16x32_bf16(aw[ks], bf, acc, 0, 0, 0);
      }
#pragma unroll
      for (int r = 0; r < 4; ++r)
        vT[((size_t)(b * C_) + 16 * wave + 4 * lq + r) * N_ + n0 + nn] = f2bf(acc[r]);
    }
  }
}

// cx reduce: cx[b][idx] = sum_seg cxp[b][seg][idx]   (cxT layout [d][c])
__global__ __launch_bounds__(256) void cxred_kernel(const float* __restrict__ cxp,
                                                    float* __restrict__ cx) {
  int idx = blockIdx.x * 256 + threadIdx.x;   // 0..16383
  int b = idx >> 12, r = idx & 4095;
  const float* p = cxp + (size_t)b * 64 * 4096 + r;
  float s = 0.f;
#pragma unroll 8
  for (int sg = 0; sg < 64; ++sg) s += p[(size_t)sg * 4096];
  cx[idx] = s;
}

// ---------------------------------------------------------------------------
// s2bf: s2[b][c][e] = sum_d cxT[d][c] * w2[d][e]  -> bf16 row-major [c][e]
// NOTE: s2bf buffer aliases a2t -> must run AFTER attn.
// ---------------------------------------------------------------------------
__global__ __launch_bounds__(256) void s2bf_kernel(const float* __restrict__ cx,
                                                   const float* __restrict__ w2,
                                                   unsigned short* __restrict__ s2bf) {
  __shared__ float cxl[4096];
  __shared__ float w2l[4096];
  int b = blockIdx.x, tid = threadIdx.x;
#pragma unroll
  for (int k = 0; k < 16; ++k) {
    int lin = tid + 256 * k;
    cxl[lin] = cx[(size_t)b * 4096 + lin];
    w2l[lin] = w2[lin];
  }
  __syncthreads();
  int c = tid & 63, eg = tid >> 6;
  float acc[16];
#pragma unroll
  for (int i = 0; i < 16; ++i) acc[i] = 0.f;
  for (int d = 0; d < 64; ++d) {
    float a = cxl[d * 64 + c];                               // per-lane cf
#pragma unroll
    for (int i = 0; i < 16; ++i) acc[i] += a * w2l[d * 64 + eg * 16 + i];  // broadcast
  }
  unsigned short* op = s2bf + (size_t)b * 4096 + c * 64 + eg * 16;
#pragma unroll
  for (int i = 0; i < 8; ++i)
    *(unsigned int*)(op + 2 * i) = pkbf(acc[2 * i], acc[2 * i + 1]);
}

// ---------------------------------------------------------------------------
// Flash attention (r14/r16/r17 kernel; only SEG=1 epilogue now writes bf16 z).
// ---------------------------------------------------------------------------
template <int SEG>
__global__ __launch_bounds__(512) void attn_kernel(const unsigned short* __restrict__ a1t,
                                                   const unsigned short* __restrict__ a2t,
                                                   const unsigned short* __restrict__ vT,
                                                   unsigned short* __restrict__ zbf,
                                                   unsigned short* __restrict__ Opart,
                                                   float* __restrict__ ml) {
  __shared__ unsigned short Kt[2][64 * 64];    // [m][c] bf16, row-XOR-swizzled
  __shared__ unsigned short Vt[2][64 * 64];    // [d][m] bf16, row-XOR-swizzled
  __shared__ uint2 Pl[8][16 * 16];             // per-wave P [q][kv] bf16, swizzled

  const int b = blockIdx.y, n0 = blockIdx.x * 128, tid = threadIdx.x;
  const int seg = (SEG > 1) ? blockIdx.z : 0;
  const int wave = tid >> 6, lane = tid & 63;
  const int l16 = lane & 15, lq = lane >> 4;
  const int NT = N_ / SEG / 64;
  const int mbase = seg * (N_ / SEG);

  const unsigned short* qbase = a1t + ((size_t)b * N_ + n0 + wave * 16 + l16) * C_;
  frag qa0 = *(const frag*)(qbase + lq * 8);
  frag qa1 = *(const frag*)(qbase + 32 + lq * 8);

  f32x4 O[4];
#pragma unroll
  for (int i = 0; i < 4; ++i) O[i] = (f32x4){0.f, 0.f, 0.f, 0.f};
  float m_l = -1e30f, l_l = 0.f;   // running max/sum for q = l16 (replicated x4)

  const unsigned short* a2b = a2t + (size_t)b * N_ * C_;
  const unsigned short* vTb = vT + (size_t)b * C_ * N_;
  char* Pw = (char*)&Pl[wave][0];
  const int swzP = (l16 & 7) << 4;

  // staging: 512 threads x 1 K-frag + 1 V-frag per tile
  const int srow = tid >> 3, scb = tid & 7;
  const int kswz = (scb * 16) ^ ((srow & 7) << 4);

  // prologue: stage tile 0
  frag k0 = *(const frag*)(a2b + (size_t)(mbase + srow) * C_ + scb * 8);
  frag v0 = *(const frag*)(vTb + (size_t)srow * N_ + mbase + scb * 8);
  *(frag*)((char*)&Kt[0][0] + srow * 128 + kswz) = k0;
  *(frag*)((char*)&Vt[0][0] + srow * 128 + kswz) = v0;
  __syncthreads();

  int cur = 0;
  for (int t = 0; t < NT; ++t, cur ^= 1) {
    // T14 issue-early: next tile's global loads in flight during compute
    if (t + 1 < NT) {
      int mn = mbase + (t + 1) * 64;
      k0 = *(const frag*)(a2b + (size_t)(mn + srow) * C_ + scb * 8);
      v0 = *(const frag*)(vTb + (size_t)srow * N_ + mn + scb * 8);
    }

    // S^T = K Q^T (swapped): lane holds S[kv=16ms+4lq+r][q=l16]
    f32x4 S[4];
    __builtin_amdgcn_s_setprio(1);
#pragma unroll
    for (int ms = 0; ms < 4; ++ms) {
      int m = ms * 16 + l16;
      int swz = (m & 7) << 4;
      frag kb0 = *(const frag*)((char*)&Kt[cur][0] + m * 128 + ((lq * 16) ^ swz));
      frag kb1 = *(const frag*)((char*)&Kt[cur][0] + m * 128 + ((64 + lq * 16) ^ swz));
      f32x4 acc = (f32x4){0.f, 0.f, 0.f, 0.f};
      acc = __builtin_amdgcn_mfma_f32_16x16x32_bf16(kb0, qa0, acc, 0, 0, 0);
      acc = __builtin_amdgcn_mfma_f32_16x16x32_bf16(kb1, qa1, acc, 0, 0, 0);
      S[ms] = acc;
    }
    __builtin_amdgcn_s_setprio(0);

    // lane-local row max (16 values) + 2-shuffle cross-lq reduce
    float mx0 = fmaxf(fmaxf(S[0][0], S[0][1]), fmaxf(S[0][2], S[0][3]));
    float mx1 = fmaxf(fmaxf(S[1][0], S[1][1]), fmaxf(S[1][2], S[1][3]));
    float mx2 = fmaxf(fmaxf(S[2][0], S[2][1]), fmaxf(S[2][2], S[2][3]));
    float mx3 = fmaxf(fmaxf(S[3][0], S[3][1]), fmaxf(S[3][2], S[3][3]));
    float mx = fmaxf(fmaxf(mx0, mx1), fmaxf(mx2, mx3));
    mx = fmaxf(mx, __shfl_xor(mx, 16, 64));
    mx = fmaxf(mx, __shfl_xor(mx, 32, 64));

    // defer-max: rescale only if some row grew by > 8
    if (!__all(mx <= m_l + 8.f)) {
      float mn = fmaxf(m_l, mx);
      float sc = __expf(m_l - mn);
      m_l = mn;
      l_l *= sc;
      float scb_[4];
#pragma unroll
      for (int r = 0; r < 4; ++r) scb_[r] = __shfl(sc, 20 * lq + r, 64);  // sc for O-row 4lq+r
#pragma unroll
      for (int ds = 0; ds < 4; ++ds)
#pragma unroll
        for (int r = 0; r < 4; ++r) O[ds][r] *= scb_[r];
    }

    // P = exp(S - m), lane-local row sum + 2 shuffles
    float p[16];
    float rs = 0.f;
#pragma unroll
    for (int ms = 0; ms < 4; ++ms)
#pragma unroll
      for (int r = 0; r < 4; ++r) {
        float e = __expf(S[ms][r] - m_l);
        p[ms * 4 + r] = e;
        rs += e;
      }
    rs += __shfl_xor(rs, 16, 64);
    rs += __shfl_xor(rs, 32, 64);
    l_l += rs;

    // P -> per-wave LDS: 4x ds_write_b64 (packed bf16), [q][kv] swizzled
#pragma unroll
    for (int ms = 0; ms < 4; ++ms) {
      uint2 w;
      w.x = pkbf(p[ms * 4 + 0], p[ms * 4 + 1]);
      w.y = pkbf(p[ms * 4 + 2], p[ms * 4 + 3]);
      *(uint2*)(Pw + l16 * 128 + ((32 * ms + 8 * lq) ^ swzP)) = w;
    }
    asm volatile("s_waitcnt lgkmcnt(0)" ::: "memory");
    __builtin_amdgcn_sched_barrier(0);  // rule 18: keep reads below the wait

    // O += P V
    frag pa0 = *(const frag*)(Pw + l16 * 128 + ((lq * 16) ^ swzP));
    frag pa1 = *(const frag*)(Pw + l16 * 128 + ((64 + lq * 16) ^ swzP));
    __builtin_amdgcn_s_setprio(1);
#pragma unroll
    for (int ds = 0; ds < 4; ++ds) {
      int d = ds * 16 + l16;
      int swz = (d & 7) << 4;
      frag vb0 = *(const frag*)((char*)&Vt[cur][0] + d * 128 + ((lq * 16) ^ swz));
      frag vb1 = *(const frag*)((char*)&Vt[cur][0] + d * 128 + ((64 + lq * 16) ^ swz));
      O[ds] = __builtin_amdgcn_mfma_f32_16x16x32_bf16(pa0, vb0, O[ds], 0, 0, 0);
      O[ds] = __builtin_amdgcn_mfma_f32_16x16x32_bf16(pa1, vb1, O[ds], 0, 0, 0);
    }
    __builtin_amdgcn_s_setprio(0);

    // ONE barrier per tile (dbuf: writes target buf[cur^1], last read at t-1)
    if (t + 1 < NT) {
      *(frag*)((char*)&Kt[cur ^ 1][0] + srow * 128 + kswz) = k0;
      *(frag*)((char*)&Vt[cur ^ 1][0] + srow * 128 + kswz) = v0;
      __syncthreads();
    }
  }

  if (SEG > 1) {
    size_t base = (size_t)(b * SEG + seg) * N_ + n0 + wave * 16;
    if (lq == 0) {       // lanes 0..15 hold q = l16 exactly
      ml[(base + l16) * 2]     = m_l;
      ml[(base + l16) * 2 + 1] = l_l;
    }
#pragma unroll
    for (int r = 0; r < 4; ++r)
#pragma unroll
      for (int ds = 0; ds < 4; ++ds)
        Opart[(base + lq * 4 + r) * 64 + ds * 16 + l16] = f2bf(O[ds][r]);
  } else {
    float inv[4];
#pragma unroll
    for (int r = 0; r < 4; ++r) inv[r] = 1.f / __shfl(l_l, 20 * lq + r, 64);
#pragma unroll
    for (int ds = 0; ds < 4; ++ds)
#pragma unroll
      for (int r = 0; r < 4; ++r)
        zbf[((size_t)b * N_ + n0 + wave * 16 + lq * 4 + r) * 128 + ds * 16 + l16] =
            f2bf(O[ds][r] * inv[r]);
  }
}

// ---------------------------------------------------------------------------
// y2 phase (shared): 64 n per block, wave w owns c-strip 16w; writes bf16 z
// ch 64..127 + per-block channel max -> mppB [B][64][64].
// ---------------------------------------------------------------------------
__device__ __forceinline__ void y2_phase(const unsigned short* __restrict__ s2bf,
                                         const unsigned short* __restrict__ a1t,
                                         unsigned short* __restrict__ zbf,
                                         float* __restrict__ mppB,
                                         f4 (*red)[4][16],
                                         int b, int blkx, int tid) {
  int n0 = blkx * 64;
  int wave = tid >> 6, lane = tid & 63, l16 = lane & 15, lq = lane >> 4;
  const unsigned short* s2r = s2bf + (size_t)b * 4096 + (16 * wave + l16) * 64;
  frag sa0 = *(const frag*)(s2r + lq * 8);
  frag sa1 = *(const frag*)(s2r + 32 + lq * 8);
  f4 mx = (f4){-1e30f, -1e30f, -1e30f, -1e30f};
#pragma unroll
  for (int ng = 0; ng < 4; ++ng) {
    const unsigned short* bp = a1t + ((size_t)b * N_ + n0 + ng * 16 + l16) * 64;
    frag b0 = *(const frag*)(bp + lq * 8);
    frag b1 = *(const frag*)(bp + 32 + lq * 8);
    f32x4 acc = (f32x4){0.f, 0.f, 0.f, 0.f};
    acc = __builtin_amdgcn_mfma_f32_16x16x32_bf16(sa0, b0, acc, 0, 0, 0);
    acc = __builtin_amdgcn_mfma_f32_16x16x32_bf16(sa1, b1, acc, 0, 0, 0);
    uint2 w;
    w.x = pkbf(acc[0], acc[1]);
    w.y = pkbf(acc[2], acc[3]);
    *(uint2*)(zbf + ((size_t)b * N_ + n0 + ng * 16 + l16) * 128 + 64 + 16 * wave + 4 * lq) = w;
#pragma unroll
    for (int r = 0; r < 4; ++r) mx[r] = fmaxf(mx[r], acc[r]);
  }
  red[wave][lq][l16] = mx;
  __syncthreads();
  if (tid < 64) {
    int w = tid >> 4, q = (tid >> 2) & 3, r = tid & 3;
    float m = -1e30f;
#pragma unroll
    for (int l = 0; l < 16; ++l) m = fmaxf(m, red[w][q][l][r]);
    mppB[((size_t)b * 64 + blkx) * 64 + 16 * w + 4 * q + r] = m;
  }
}

// combine SEG partials -> bf16 z[ch 0..63] + mppA; fused y2 -> ch 64..127 + mppB
template <int SEG>
__global__ __launch_bounds__(256) void combineY2_kernel(const unsigned short* __restrict__ Opart,
                                                        const float* __restrict__ ml,
                                                        const unsigned short* __restrict__ s2bf,
                                                        const unsigned short* __restrict__ a1t,
                                                        unsigned short* __restrict__ zbf,
                                                        float* __restrict__ mppA,
                                                        float* __restrict__ mppB) {
  __shared__ float zsm[64][65];
  __shared__ f4 red[4][4][16];
  int b = blockIdx.y, tid = threadIdx.x;
  int nr = tid >> 2;
  int n = blockIdx.x * 64 + nr;
  int dq = (tid & 3) * 16;
  float mv[SEG], lv[SEG], M = -1e30f;
#pragma unroll
  for (int s = 0; s < SEG; ++s) {
    size_t r = (size_t)(b * SEG + s) * N_ + n;
    mv[s] = ml[r * 2];
    lv[s] = ml[r * 2 + 1];
    M = fmaxf(M, mv[s]);
  }
  float acc[16];
#pragma unroll
  for (int j = 0; j < 16; ++j) acc[j] = 0.f;
  float l = 0.f;
#pragma unroll
  for (int s = 0; s < SEG; ++s) {
    float w = __expf(mv[s] - M);
    l += w * lv[s];
    const unsigned short* op = Opart + ((size_t)(b * SEG + s) * N_ + n) * 64 + dq;
    frag p0 = *(const frag*)(op);
    frag p1 = *(const frag*)(op + 8);
#pragma unroll
    for (int j = 0; j < 8; ++j) {
      acc[j]     += w * bf2f((unsigned short)p0[j]);
      acc[8 + j] += w * bf2f((unsigned short)p1[j]);
    }
  }
  float inv = 1.f / l;
  unsigned int zw[8];
#pragma unroll
  for (int j = 0; j < 16; ++j) acc[j] *= inv;
#pragma unroll
  for (int k = 0; k < 8; ++k) zw[k] = pkbf(acc[2 * k], acc[2 * k + 1]);
  {  // bf16 z write: 16 ch = 32 B via two uint4 (16B-aligned: dq mult of 16)
    unsigned short* zp = zbf + ((size_t)b * N_ + n) * 128 + dq;
    *(uint4*)(zp)     = (uint4){zw[0], zw[1], zw[2], zw[3]};
    *(uint4*)(zp + 8) = (uint4){zw[4], zw[5], zw[6], zw[7]};
  }
#pragma unroll
  for (int j = 0; j < 16; ++j) zsm[nr][dq + j] = acc[j];
  __syncthreads();
  if (tid < 64) {
    float mx = -1e30f;
    for (int nn = 0; nn < 64; ++nn) mx = fmaxf(mx, zsm[nn][tid]);
    mppA[((size_t)b * 64 + blockIdx.x) * 64 + tid] = mx;
  }
  // fused y2 for the same 64 n-rows (has its own barrier inside)
  y2_phase(s2bf, a1t, zbf, mppB, red, b, blockIdx.x, tid);
}

// SEG=1 fallbacks
__global__ __launch_bounds__(256) void mpA_kernel(const unsigned short* __restrict__ zbf,
                                                  float* __restrict__ mppA) {
  __shared__ float red[4][64];
  int b = blockIdx.y, n0 = blockIdx.x * 64, tid = threadIdx.x;
  int e = tid & 63, g = tid >> 6;
  float mx = -1e30f;
#pragma unroll
  for (int k = 0; k < 16; ++k)
    mx = fmaxf(mx, bf2f(zbf[((size_t)b * N_ + n0 + g + 4 * k) * 128 + e]));
  red[g][e] = mx;
  __syncthreads();
  if (tid < 64)
    mppA[((size_t)b * 64 + blockIdx.x) * 64 + tid] =
        fmaxf(fmaxf(red[0][tid], red[1][tid]), fmaxf(red[2][tid], red[3][tid]));
}

__global__ __launch_bounds__(256) void y2_kernel(const unsigned short* __restrict__ s2bf,
                                                 const unsigned short* __restrict__ a1t,
                                                 unsigned short* __restrict__ zbf,
                                                 float* __restrict__ mppB) {
  __shared__ f4 red[4][4][16];
  y2_phase(s2bf, a1t, zbf, mppB, red, blockIdx.y, blockIdx.x, threadIdx.x);
}

// ---------------------------------------------------------------------------
// ca2: full channel attention, one block per batch. mppA, mppB [B][64][64].
// ---------------------------------------------------------------------------
__global__ __launch_bounds__(256) void ca2_kernel(const float* __restrict__ mppA,
                                                  const float* __restrict__ mppB,
                                                  const float* __restrict__ fc1,
                                                  const float* __restrict__ fc2,
                                                  float* __restrict__ vbuf) {
  __shared__ f4 red4[256];
  __shared__ float mpl[128];
  __shared__ float red2[8][33];
  __shared__ float hl[8];
  int b = blockIdx.x, t = threadIdx.x;
  {
    const f4* src = (const f4*)(mppA + (size_t)b * 64 * 64);
    f4 m = src[t];
    m = max4(m, src[t + 256]);
    m = max4(m, src[t + 512]);
    m = max4(m, src[t + 768]);
    red4[t] = m;
  }
  __syncthreads();
  if (t < 16) {
    f4 m = red4[t];
#pragma unroll
    for (int j = 1; j < 16; ++j) m = max4(m, red4[t + 16 * j]);
    *(f4*)&mpl[t * 4] = m;
  }
  __syncthreads();
  {
    const f4* src = (const f4*)(mppB + (size_t)b * 64 * 64);
    f4 m = src[t];
    m = max4(m, src[t + 256]);
    m = max4(m, src[t + 512]);
    m = max4(m, src[t + 768]);
    red4[t] = m;
  }
  __syncthreads();
  if (t < 16) {
    f4 m = red4[t];
#pragma unroll
    for (int j = 1; j < 16; ++j) m = max4(m, red4[t + 16 * j]);
    *(f4*)&mpl[64 + t * 4] = m;
  }
  __syncthreads();
  {
    int r = t >> 5, j = t & 31;
    const f4 mv = *(const f4*)&mpl[j * 4];
    const f4 wv = *(const f4*)(fc1 + r * 128 + j * 4);
    red2[r][j] = mv.x * wv.x + mv.y * wv.y + mv.z * wv.z + mv.w * wv.w;
  }
  __syncthreads();
  if (t < 8) {
    float s = 0.f;
#pragma unroll
    for (int j = 0; j < 32; ++j) s += red2[t][j];
    hl[t] = fmaxf(s, 0.f);
  }
  __syncthreads();
  if (t < 128) {
    float s = 0.f;
    const float* f2r = fc2 + t * 8;
#pragma unroll
    for (int r = 0; r < 8; ++r) s += hl[r] * f2r[r];
    vbuf[b * 128 + t] = 1.f + 1.f / (1.f + __expf(-s));
  }
}

// ---------------------------------------------------------------------------
// final 1x1 conv via MFMA, LDS-free (y2 pattern, K=128):
// out[b][o][n] = sum_e zbf[n][e] * (v[e]*cw[o][e]) + conv_b[o]
// v folded into A-fragments; B-frags straight from global bf16 z rows.
// Grid (128, B): 32 n per block; wave w owns o-strip 16w.
// ---------------------------------------------------------------------------
__global__ __launch_bounds__(256) void conv_kernel(const unsigned short* __restrict__ zbf,
                                                   const float* __restrict__ vbuf,
                                                   const float* __restrict__ conv_w,
                                                   const float* __restrict__ conv_b,
                                                   float* __restrict__ out) {
  int b = blockIdx.y, n0 = blockIdx.x * 32, tid = threadIdx.x;
  int wave = tid >> 6, lane = tid & 63, l16 = lane & 15, lq = lane >> 4;
  // A = cw[o][e] * v[e], o = 16w + l16, 4 k-chunks of 32 e
  const float* cwr = conv_w + (size_t)(16 * wave + l16) * 128 + lq * 8;
  const float* vbr = vbuf + b * 128 + lq * 8;
  frag aw[4];
#pragma unroll
  for (int ks = 0; ks < 4; ++ks) {
    f4 c0 = *(const f4*)(cwr + ks * 32);
    f4 c1 = *(const f4*)(cwr + ks * 32 + 4);
    f4 v0 = *(const f4*)(vbr + ks * 32);
    f4 v1 = *(const f4*)(vbr + ks * 32 + 4);
    aw[ks] = pk8(c0 * v0, c1 * v1);
  }
  f32x4 acc[2];
#pragma unroll
  for (int ng = 0; ng < 2; ++ng) acc[ng] = (f32x4){0.f, 0.f, 0.f, 0.f};
#pragma unroll
  for (int ng = 0; ng < 2; ++ng) {
    const unsigned short* zr = zbf + ((size_t)b * N_ + n0 + ng * 16 + l16) * 128;
#pragma unroll
    for (int ks = 0; ks < 4; ++ks) {
      frag bz = *(const frag*)(zr + ks * 32 + lq * 8);
      acc[ng] = __builtin_amdgcn_mfma_f32_16x16x32_bf16(aw[ks], bz, acc[ng], 0, 0, 0);
    }
  }
#pragma unroll
  for (int r = 0; r < 4; ++r) {
    int o = 16 * wave + 4 * lq + r;
    float bias = conv_b[o];
#pragma unroll
    for (int ng = 0; ng < 2; ++ng)
      out[((size_t)(b * C_ + o)) * N_ + n0 + ng * 16 + l16] = acc[ng][r] + bias;
  }
}

// ---------------------------------------------------------------------------
extern "C" void kernel_launch(void* const* d_in, const int* in_sizes, int n_in,
                              void* d_out, int out_size, void* d_ws, size_t ws_size,
                              hipStream_t stream) {
  const float* x1      = (const float*)d_in[0];
  const float* x2      = (const float*)d_in[1];
  const float* weight  = (const float*)d_in[2];
  const float* weight2 = (const float*)d_in[3];
  const float* fc1     = (const float*)d_in[4];
  const float* fc2     = (const float*)d_in[5];
  const float* conv_w  = (const float*)d_in[6];
  const float* conv_b  = (const float*)d_in[7];
  float* out = (float*)d_out;

  // workspace layout
  char* ws = (char*)d_ws;
  unsigned short* a1t = (unsigned short*)(ws + 0);          // 2 MB bf16 [B][N][C]
  unsigned short* a2t = (unsigned short*)(ws + 2097152);    // 2 MB bf16 [B][N][C]
  // post-attn aliases of the a2t region:
  float* mppA = (float*)(ws + 2097152);                     // 64 KB [B][64][64]
  float* mppB = (float*)(ws + 2162688);                     // 64 KB [B][64][64]
  unsigned short* s2bf = (unsigned short*)(ws + 2293760);   // 32 KB bf16 [B][C][C]
  unsigned short* vT  = (unsigned short*)(ws + 4194304);    // 2 MB bf16 [B][C][N]
  unsigned short* zbf = (unsigned short*)(ws + 6291456);    // 4 MB bf16 [B][N][2C]
  float* cxp  = (float*)(ws + 10485760);                    // 4 MB fp32 [B][64][4096]
  float* cx   = (float*)(ws + 14680064);                    // 64 KB [B][64*64] (cxT: [d][c])
  float* vbuf = (float*)(ws + 14745600);                    // 2 KB  [B][128]
  unsigned short* Opart = (unsigned short*)(ws + 14764544); // 8 MB bf16 [B][4][N][64]
  float* ml   = (float*)(ws + 23153152);                    // 512 KB [B][4][N][2]
  const bool seg4 = ws_size >= 23677440ull;

  prep_kernel<<<dim3(64, 4), 256, 0, stream>>>(x1, x2, weight, a1t, a2t, vT, cxp);
  cxred_kernel<<<dim3(64), 256, 0, stream>>>(cxp, cx);
  if (seg4) {
    attn_kernel<4><<<dim3(32, 4, 4), 512, 0, stream>>>(a1t, a2t, vT, zbf, Opart, ml);
    s2bf_kernel<<<dim3(4), 256, 0, stream>>>(cx, weight2, s2bf);    // a2t dead now
    combineY2_kernel<4><<<dim3(64, 4), 256, 0, stream>>>(Opart, ml, s2bf, a1t, zbf, mppA, mppB);
  } else {
    attn_kernel<1><<<dim3(32, 4), 512, 0, stream>>>(a1t, a2t, vT, zbf, nullptr, nullptr);
    s2bf_kernel<<<dim3(4), 256, 0, stream>>>(cx, weight2, s2bf);
    mpA_kernel<<<dim3(64, 4), 256, 0, stream>>>(zbf, mppA);
    y2_kernel<<<dim3(64, 4), 256, 0, stream>>>(s2bf, a1t, zbf, mppB);
  }
  ca2_kernel<<<dim3(4), 256, 0, stream>>>(mppA, mppB, fc1, fc2, vbuf);
  conv_kernel<<<dim3(128, 4), 256, 0, stream>>>(zbf, vbuf, conv_w, conv_b, out);
}

// Round 19
// 68.395 us; speedup vs baseline: 1.1077x; 1.0159x over previous
//
#include <hip/hip_runtime.h>
#include <hip/hip_bf16.h>
#include <math.h>

// Problem constants (B,C,H,W = 4,64,64,64)
#define B_   4
#define C_   64
#define N_   4096   // H*W
#define C2_  128

using frag  = __attribute__((ext_vector_type(8))) short;  // 8 bf16 (4 VGPRs)
using f32x4 = __attribute__((ext_vector_type(4))) float;
using f4    = __attribute__((ext_vector_type(4))) float;

__device__ __forceinline__ unsigned short f2bf(float f) {
  unsigned int u = __float_as_uint(f);
  u += 0x7fffu + ((u >> 16) & 1u);   // RNE
  return (unsigned short)(u >> 16);
}
__device__ __forceinline__ float bf2f(unsigned short h) {
  return __uint_as_float(((unsigned int)h) << 16);
}
// pack 2 floats -> 2 bf16 in one u32 (compiler fuses to v_cvt_pk_bf16_f32)
__device__ __forceinline__ unsigned int pkbf(float a, float b) {
  __hip_bfloat16 ha = __float2bfloat16(a), hb = __float2bfloat16(b);
  unsigned short ua, ub;
  __builtin_memcpy(&ua, &ha, 2);
  __builtin_memcpy(&ub, &hb, 2);
  return (unsigned int)ua | ((unsigned int)ub << 16);
}
// 8 fp32 -> bf16 A/B fragment
__device__ __forceinline__ frag pk8(f4 lo, f4 hi) {
  frag f;
  unsigned int* u = (unsigned int*)&f;
  u[0] = pkbf(lo.x, lo.y);
  u[1] = pkbf(lo.z, lo.w);
  u[2] = pkbf(hi.x, hi.y);
  u[3] = pkbf(hi.z, hi.w);
  return f;
}
__device__ __forceinline__ f4 max4(f4 a, f4 b) {
  return (f4){fmaxf(a.x, b.x), fmaxf(a.y, b.y), fmaxf(a.z, b.z), fmaxf(a.w, b.w)};
}

// ---------------------------------------------------------------------------
// prep + cx + support fused (r16/r17, unchanged): stage x1,x2 64-n tiles + W;
// emit a1t,a2t bf16 [N][C]; cxp partial (MFMA); vT (MFMA).
// ---------------------------------------------------------------------------
__global__ __launch_bounds__(256) void prep_kernel(const float* __restrict__ x1,
                                                   const float* __restrict__ x2,
                                                   const float* __restrict__ weight,
                                                   unsigned short* __restrict__ a1t,
                                                   unsigned short* __restrict__ a2t,
                                                   unsigned short* __restrict__ vT,
                                                   float* __restrict__ cxp) {
  __shared__ float tA[64 * 65];   // x2 [c][n], padded
  __shared__ float tB[64 * 65];   // x1
  __shared__ float Wl[64 * 65];   // W  [c][d], padded
  int b = blockIdx.y, n0 = blockIdx.x * 64, tid = threadIdx.x;
  int wave = tid >> 6, lane = tid & 63, l16 = lane & 15, lq = lane >> 4;
  {
    int n = tid & 63, cq = tid >> 6;
#pragma unroll
    for (int k = 0; k < 16; ++k) {
      int c = cq + 4 * k;
      tA[c * 65 + n] = x2[((size_t)(b * C_ + c)) * N_ + n0 + n];   // coalesced
      tB[c * 65 + n] = x1[((size_t)(b * C_ + c)) * N_ + n0 + n];
      Wl[c * 65 + n] = weight[c * 64 + n];                          // [c][d]
    }
  }
  __syncthreads();
  {  // transpose-out (stride-65 conflict-free reads, coalesced writes)
    int c = tid & 63, nq = tid >> 6;
#pragma unroll
    for (int k = 0; k < 16; ++k) {
      int n2 = nq + 4 * k;
      a2t[((size_t)b * N_ + n0 + n2) * C_ + c] = f2bf(tA[c * 65 + n2]);
      a1t[((size_t)b * N_ + n0 + n2) * C_ + c] = f2bf(tB[c * 65 + n2]);
    }
  }
  {  // cx partial via MFMA: cxp[d*64+c] = sum_n x2[d][n]*x1[c][n]
    int dd = 16 * wave + l16;
    frag afr[2];
#pragma unroll
    for (int ks = 0; ks < 2; ++ks) {
      float w0[8];
#pragma unroll
      for (int j = 0; j < 8; ++j) w0[j] = tA[dd * 65 + ks * 32 + lq * 8 + j];
      afr[ks] = pk8((f4){w0[0], w0[1], w0[2], w0[3]}, (f4){w0[4], w0[5], w0[6], w0[7]});
    }
    f32x4 acc[4];
#pragma unroll
    for (int cg = 0; cg < 4; ++cg) acc[cg] = (f32x4){0.f, 0.f, 0.f, 0.f};
#pragma unroll
    for (int cg = 0; cg < 4; ++cg) {
      int cc = cg * 16 + l16;
#pragma unroll
      for (int ks = 0; ks < 2; ++ks) {
        float w0[8];
#pragma unroll
        for (int j = 0; j < 8; ++j) w0[j] = tB[cc * 65 + ks * 32 + lq * 8 + j];
        frag bfr = pk8((f4){w0[0], w0[1], w0[2], w0[3]}, (f4){w0[4], w0[5], w0[6], w0[7]});
        acc[cg] = __builtin_amdgcn_mfma_f32_16x16x32_bf16(afr[ks], bfr, acc[cg], 0, 0, 0);
      }
    }
    float* op = cxp + ((size_t)(b * 64 + blockIdx.x)) * 4096;
#pragma unroll
    for (int cg = 0; cg < 4; ++cg)
#pragma unroll
      for (int r = 0; r < 4; ++r)
        op[(16 * wave + 4 * lq + r) * 64 + cg * 16 + l16] = acc[cg][r];
  }
  {  // vT via MFMA: vT[d][n] = sum_c W[c][d] * x2[c][n]
    int dd = 16 * wave + l16;
    frag aw[2];
#pragma unroll
    for (int ks = 0; ks < 2; ++ks) {
      float wv[8];
#pragma unroll
      for (int j = 0; j < 8; ++j) wv[j] = Wl[(ks * 32 + lq * 8 + j) * 65 + dd];  // 2-way free
      aw[ks] = pk8((f4){wv[0], wv[1], wv[2], wv[3]}, (f4){wv[4], wv[5], wv[6], wv[7]});
    }
#pragma unroll
    for (int ng = 0; ng < 4; ++ng) {
      int nn = ng * 16 + l16;
      f32x4 acc = (f32x4){0.f, 0.f, 0.f, 0.f};
#pragma unroll
      for (int ks = 0; ks < 2; ++ks) {
        float bx[8];
#pragma unroll
        for (int j = 0; j < 8; ++j) bx[j] = tA[(ks * 32 + lq * 8 + j) * 65 + nn];  // cf banks
        frag bf = pk8((f4){bx[0], bx[1], bx[2], bx[3]}, (f4){bx[4], bx[5], bx[6], bx[7]});
        acc = __builtin_amdgcn_mfma_f32_16x16x32_bf16(aw[ks], bf, acc, 0, 0, 0);
      }
#pragma unroll
      for (int r = 0; r < 4; ++r)
        vT[((size_t)(b * C_) + 16 * wave + 4 * lq + r) * N_ + n0 + nn] = f2bf(acc[r]);
    }
  }
}

// cx reduce: cx[b][idx] = sum_seg cxp[b][seg][idx]   (cxT layout [d][c])
__global__ __launch_bounds__(256) void cxred_kernel(const float* __restrict__ cxp,
                                                    float* __restrict__ cx) {
  int idx = blockIdx.x * 256 + threadIdx.x;   // 0..16383
  int b = idx >> 12, r = idx & 4095;
  const float* p = cxp + (size_t)b * 64 * 4096 + r;
  float s = 0.f;
#pragma unroll 8
  for (int sg = 0; sg < 64; ++sg) s += p[(size_t)sg * 4096];
  cx[idx] = s;
}

// ---------------------------------------------------------------------------
// s2bf: s2[b][c][e] = sum_d cxT[d][c] * w2[d][e]  -> bf16 row-major [c][e]
// NOTE: s2bf buffer aliases a2t -> must run AFTER attn.
// ---------------------------------------------------------------------------
__global__ __launch_bounds__(256) void s2bf_kernel(const float* __restrict__ cx,
                                                   const float* __restrict__ w2,
                                                   unsigned short* __restrict__ s2bf) {
  __shared__ float cxl[4096];
  __shared__ float w2l[4096];
  int b = blockIdx.x, tid = threadIdx.x;
#pragma unroll
  for (int k = 0; k < 16; ++k) {
    int lin = tid + 256 * k;
    cxl[lin] = cx[(size_t)b * 4096 + lin];
    w2l[lin] = w2[lin];
  }
  __syncthreads();
  int c = tid & 63, eg = tid >> 6;
  float acc[16];
#pragma unroll
  for (int i = 0; i < 16; ++i) acc[i] = 0.f;
  for (int d = 0; d < 64; ++d) {
    float a = cxl[d * 64 + c];                               // per-lane cf
#pragma unroll
    for (int i = 0; i < 16; ++i) acc[i] += a * w2l[d * 64 + eg * 16 + i];  // broadcast
  }
  unsigned short* op = s2bf + (size_t)b * 4096 + c * 64 + eg * 16;
#pragma unroll
  for (int i = 0; i < 8; ++i)
    *(unsigned int*)(op + 2 * i) = pkbf(acc[2 * i], acc[2 * i + 1]);
}

// ---------------------------------------------------------------------------
// Flash attention (r18 kernel; ONLY delta: softmax-denominator cross-lane
// reduce deferred to the epilogue — l_l is a lane-local partial in the loop).
// ---------------------------------------------------------------------------
template <int SEG>
__global__ __launch_bounds__(512) void attn_kernel(const unsigned short* __restrict__ a1t,
                                                   const unsigned short* __restrict__ a2t,
                                                   const unsigned short* __restrict__ vT,
                                                   unsigned short* __restrict__ zbf,
                                                   unsigned short* __restrict__ Opart,
                                                   float* __restrict__ ml) {
  __shared__ unsigned short Kt[2][64 * 64];    // [m][c] bf16, row-XOR-swizzled
  __shared__ unsigned short Vt[2][64 * 64];    // [d][m] bf16, row-XOR-swizzled
  __shared__ uint2 Pl[8][16 * 16];             // per-wave P [q][kv] bf16, swizzled

  const int b = blockIdx.y, n0 = blockIdx.x * 128, tid = threadIdx.x;
  const int seg = (SEG > 1) ? blockIdx.z : 0;
  const int wave = tid >> 6, lane = tid & 63;
  const int l16 = lane & 15, lq = lane >> 4;
  const int NT = N_ / SEG / 64;
  const int mbase = seg * (N_ / SEG);

  const unsigned short* qbase = a1t + ((size_t)b * N_ + n0 + wave * 16 + l16) * C_;
  frag qa0 = *(const frag*)(qbase + lq * 8);
  frag qa1 = *(const frag*)(qbase + 32 + lq * 8);

  f32x4 O[4];
#pragma unroll
  for (int i = 0; i < 4; ++i) O[i] = (f32x4){0.f, 0.f, 0.f, 0.f};
  float m_l = -1e30f, l_l = 0.f;   // m: running max (q=l16); l: LANE-LOCAL partial sum

  const unsigned short* a2b = a2t + (size_t)b * N_ * C_;
  const unsigned short* vTb = vT + (size_t)b * C_ * N_;
  char* Pw = (char*)&Pl[wave][0];
  const int swzP = (l16 & 7) << 4;

  // staging: 512 threads x 1 K-frag + 1 V-frag per tile
  const int srow = tid >> 3, scb = tid & 7;
  const int kswz = (scb * 16) ^ ((srow & 7) << 4);

  // prologue: stage tile 0
  frag k0 = *(const frag*)(a2b + (size_t)(mbase + srow) * C_ + scb * 8);
  frag v0 = *(const frag*)(vTb + (size_t)srow * N_ + mbase + scb * 8);
  *(frag*)((char*)&Kt[0][0] + srow * 128 + kswz) = k0;
  *(frag*)((char*)&Vt[0][0] + srow * 128 + kswz) = v0;
  __syncthreads();

  int cur = 0;
  for (int t = 0; t < NT; ++t, cur ^= 1) {
    // T14 issue-early: next tile's global loads in flight during compute
    if (t + 1 < NT) {
      int mn = mbase + (t + 1) * 64;
      k0 = *(const frag*)(a2b + (size_t)(mn + srow) * C_ + scb * 8);
      v0 = *(const frag*)(vTb + (size_t)srow * N_ + mn + scb * 8);
    }

    // S^T = K Q^T (swapped): lane holds S[kv=16ms+4lq+r][q=l16]
    f32x4 S[4];
    __builtin_amdgcn_s_setprio(1);
#pragma unroll
    for (int ms = 0; ms < 4; ++ms) {
      int m = ms * 16 + l16;
      int swz = (m & 7) << 4;
      frag kb0 = *(const frag*)((char*)&Kt[cur][0] + m * 128 + ((lq * 16) ^ swz));
      frag kb1 = *(const frag*)((char*)&Kt[cur][0] + m * 128 + ((64 + lq * 16) ^ swz));
      f32x4 acc = (f32x4){0.f, 0.f, 0.f, 0.f};
      acc = __builtin_amdgcn_mfma_f32_16x16x32_bf16(kb0, qa0, acc, 0, 0, 0);
      acc = __builtin_amdgcn_mfma_f32_16x16x32_bf16(kb1, qa1, acc, 0, 0, 0);
      S[ms] = acc;
    }
    __builtin_amdgcn_s_setprio(0);

    // lane-local row max (16 values) + 2-shuffle cross-lq reduce
    float mx0 = fmaxf(fmaxf(S[0][0], S[0][1]), fmaxf(S[0][2], S[0][3]));
    float mx1 = fmaxf(fmaxf(S[1][0], S[1][1]), fmaxf(S[1][2], S[1][3]));
    float mx2 = fmaxf(fmaxf(S[2][0], S[2][1]), fmaxf(S[2][2], S[2][3]));
    float mx3 = fmaxf(fmaxf(S[3][0], S[3][1]), fmaxf(S[3][2], S[3][3]));
    float mx = fmaxf(fmaxf(mx0, mx1), fmaxf(mx2, mx3));
    mx = fmaxf(mx, __shfl_xor(mx, 16, 64));
    mx = fmaxf(mx, __shfl_xor(mx, 32, 64));

    // defer-max: rescale only if some row grew by > 8.
    // sc is uniform across the 4 lq-replicas of each q -> lane-local l partial
    // rescales correctly.
    if (!__all(mx <= m_l + 8.f)) {
      float mn = fmaxf(m_l, mx);
      float sc = __expf(m_l - mn);
      m_l = mn;
      l_l *= sc;
      float scb_[4];
#pragma unroll
      for (int r = 0; r < 4; ++r) scb_[r] = __shfl(sc, 20 * lq + r, 64);  // sc for O-row 4lq+r
#pragma unroll
      for (int ds = 0; ds < 4; ++ds)
#pragma unroll
        for (int r = 0; r < 4; ++r) O[ds][r] *= scb_[r];
    }

    // P = exp(S - m); accumulate LANE-LOCAL sum only (cross-lane deferred)
    float p[16];
    float rs = 0.f;
#pragma unroll
    for (int ms = 0; ms < 4; ++ms)
#pragma unroll
      for (int r = 0; r < 4; ++r) {
        float e = __expf(S[ms][r] - m_l);
        p[ms * 4 + r] = e;
        rs += e;
      }
    l_l += rs;

    // P -> per-wave LDS: 4x ds_write_b64 (packed bf16), [q][kv] swizzled
#pragma unroll
    for (int ms = 0; ms < 4; ++ms) {
      uint2 w;
      w.x = pkbf(p[ms * 4 + 0], p[ms * 4 + 1]);
      w.y = pkbf(p[ms * 4 + 2], p[ms * 4 + 3]);
      *(uint2*)(Pw + l16 * 128 + ((32 * ms + 8 * lq) ^ swzP)) = w;
    }
    asm volatile("s_waitcnt lgkmcnt(0)" ::: "memory");
    __builtin_amdgcn_sched_barrier(0);  // rule 18: keep reads below the wait

    // O += P V
    frag pa0 = *(const frag*)(Pw + l16 * 128 + ((lq * 16) ^ swzP));
    frag pa1 = *(const frag*)(Pw + l16 * 128 + ((64 + lq * 16) ^ swzP));
    __builtin_amdgcn_s_setprio(1);
#pragma unroll
    for (int ds = 0; ds < 4; ++ds) {
      int d = ds * 16 + l16;
      int swz = (d & 7) << 4;
      frag vb0 = *(const frag*)((char*)&Vt[cur][0] + d * 128 + ((lq * 16) ^ swz));
      frag vb1 = *(const frag*)((char*)&Vt[cur][0] + d * 128 + ((64 + lq * 16) ^ swz));
      O[ds] = __builtin_amdgcn_mfma_f32_16x16x32_bf16(pa0, vb0, O[ds], 0, 0, 0);
      O[ds] = __builtin_amdgcn_mfma_f32_16x16x32_bf16(pa1, vb1, O[ds], 0, 0, 0);
    }
    __builtin_amdgcn_s_setprio(0);

    // ONE barrier per tile (dbuf: writes target buf[cur^1], last read at t-1)
    if (t + 1 < NT) {
      *(frag*)((char*)&Kt[cur ^ 1][0] + srow * 128 + kswz) = k0;
      *(frag*)((char*)&Vt[cur ^ 1][0] + srow * 128 + kswz) = v0;
      __syncthreads();
    }
  }

  // deferred cross-lane l reduce: 2 shuffles total (was 2 per tile)
  l_l += __shfl_xor(l_l, 16, 64);
  l_l += __shfl_xor(l_l, 32, 64);

  if (SEG > 1) {
    size_t base = (size_t)(b * SEG + seg) * N_ + n0 + wave * 16;
    if (lq == 0) {       // lanes 0..15 hold q = l16 exactly
      ml[(base + l16) * 2]     = m_l;
      ml[(base + l16) * 2 + 1] = l_l;
    }
#pragma unroll
    for (int r = 0; r < 4; ++r)
#pragma unroll
      for (int ds = 0; ds < 4; ++ds)
        Opart[(base + lq * 4 + r) * 64 + ds * 16 + l16] = f2bf(O[ds][r]);
  } else {
    float inv[4];
#pragma unroll
    for (int r = 0; r < 4; ++r) inv[r] = 1.f / __shfl(l_l, 20 * lq + r, 64);
#pragma unroll
    for (int ds = 0; ds < 4; ++ds)
#pragma unroll
      for (int r = 0; r < 4; ++r)
        zbf[((size_t)b * N_ + n0 + wave * 16 + lq * 4 + r) * 128 + ds * 16 + l16] =
            f2bf(O[ds][r] * inv[r]);
  }
}

// ---------------------------------------------------------------------------
// y2 phase (shared): 64 n per block, wave w owns c-strip 16w; writes bf16 z
// ch 64..127 + per-block channel max -> mppB [B][64][64].
// ---------------------------------------------------------------------------
__device__ __forceinline__ void y2_phase(const unsigned short* __restrict__ s2bf,
                                         const unsigned short* __restrict__ a1t,
                                         unsigned short* __restrict__ zbf,
                                         float* __restrict__ mppB,
                                         f4 (*red)[4][16],
                                         int b, int blkx, int tid) {
  int n0 = blkx * 64;
  int wave = tid >> 6, lane = tid & 63, l16 = lane & 15, lq = lane >> 4;
  const unsigned short* s2r = s2bf + (size_t)b * 4096 + (16 * wave + l16) * 64;
  frag sa0 = *(const frag*)(s2r + lq * 8);
  frag sa1 = *(const frag*)(s2r + 32 + lq * 8);
  f4 mx = (f4){-1e30f, -1e30f, -1e30f, -1e30f};
#pragma unroll
  for (int ng = 0; ng < 4; ++ng) {
    const unsigned short* bp = a1t + ((size_t)b * N_ + n0 + ng * 16 + l16) * 64;
    frag b0 = *(const frag*)(bp + lq * 8);
    frag b1 = *(const frag*)(bp + 32 + lq * 8);
    f32x4 acc = (f32x4){0.f, 0.f, 0.f, 0.f};
    acc = __builtin_amdgcn_mfma_f32_16x16x32_bf16(sa0, b0, acc, 0, 0, 0);
    acc = __builtin_amdgcn_mfma_f32_16x16x32_bf16(sa1, b1, acc, 0, 0, 0);
    uint2 w;
    w.x = pkbf(acc[0], acc[1]);
    w.y = pkbf(acc[2], acc[3]);
    *(uint2*)(zbf + ((size_t)b * N_ + n0 + ng * 16 + l16) * 128 + 64 + 16 * wave + 4 * lq) = w;
#pragma unroll
    for (int r = 0; r < 4; ++r) mx[r] = fmaxf(mx[r], acc[r]);
  }
  red[wave][lq][l16] = mx;
  __syncthreads();
  if (tid < 64) {
    int w = tid >> 4, q = (tid >> 2) & 3, r = tid & 3;
    float m = -1e30f;
#pragma unroll
    for (int l = 0; l < 16; ++l) m = fmaxf(m, red[w][q][l][r]);
    mppB[((size_t)b * 64 + blkx) * 64 + 16 * w + 4 * q + r] = m;
  }
}

// combine SEG partials -> bf16 z[ch 0..63] + mppA; fused y2 -> ch 64..127 + mppB
template <int SEG>
__global__ __launch_bounds__(256) void combineY2_kernel(const unsigned short* __restrict__ Opart,
                                                        const float* __restrict__ ml,
                                                        const unsigned short* __restrict__ s2bf,
                                                        const unsigned short* __restrict__ a1t,
                                                        unsigned short* __restrict__ zbf,
                                                        float* __restrict__ mppA,
                                                        float* __restrict__ mppB) {
  __shared__ float zsm[64][65];
  __shared__ f4 red[4][4][16];
  int b = blockIdx.y, tid = threadIdx.x;
  int nr = tid >> 2;
  int n = blockIdx.x * 64 + nr;
  int dq = (tid & 3) * 16;
  float mv[SEG], lv[SEG], M = -1e30f;
#pragma unroll
  for (int s = 0; s < SEG; ++s) {
    size_t r = (size_t)(b * SEG + s) * N_ + n;
    mv[s] = ml[r * 2];
    lv[s] = ml[r * 2 + 1];
    M = fmaxf(M, mv[s]);
  }
  float acc[16];
#pragma unroll
  for (int j = 0; j < 16; ++j) acc[j] = 0.f;
  float l = 0.f;
#pragma unroll
  for (int s = 0; s < SEG; ++s) {
    float w = __expf(mv[s] - M);
    l += w * lv[s];
    const unsigned short* op = Opart + ((size_t)(b * SEG + s) * N_ + n) * 64 + dq;
    frag p0 = *(const frag*)(op);
    frag p1 = *(const frag*)(op + 8);
#pragma unroll
    for (int j = 0; j < 8; ++j) {
      acc[j]     += w * bf2f((unsigned short)p0[j]);
      acc[8 + j] += w * bf2f((unsigned short)p1[j]);
    }
  }
  float inv = 1.f / l;
  unsigned int zw[8];
#pragma unroll
  for (int j = 0; j < 16; ++j) acc[j] *= inv;
#pragma unroll
  for (int k = 0; k < 8; ++k) zw[k] = pkbf(acc[2 * k], acc[2 * k + 1]);
  {  // bf16 z write: 16 ch = 32 B via two uint4 (16B-aligned: dq mult of 16)
    unsigned short* zp = zbf + ((size_t)b * N_ + n) * 128 + dq;
    *(uint4*)(zp)     = (uint4){zw[0], zw[1], zw[2], zw[3]};
    *(uint4*)(zp + 8) = (uint4){zw[4], zw[5], zw[6], zw[7]};
  }
#pragma unroll
  for (int j = 0; j < 16; ++j) zsm[nr][dq + j] = acc[j];
  __syncthreads();
  if (tid < 64) {
    float mx = -1e30f;
    for (int nn = 0; nn < 64; ++nn) mx = fmaxf(mx, zsm[nn][tid]);
    mppA[((size_t)b * 64 + blockIdx.x) * 64 + tid] = mx;
  }
  // fused y2 for the same 64 n-rows (has its own barrier inside)
  y2_phase(s2bf, a1t, zbf, mppB, red, b, blockIdx.x, tid);
}

// SEG=1 fallbacks
__global__ __launch_bounds__(256) void mpA_kernel(const unsigned short* __restrict__ zbf,
                                                  float* __restrict__ mppA) {
  __shared__ float red[4][64];
  int b = blockIdx.y, n0 = blockIdx.x * 64, tid = threadIdx.x;
  int e = tid & 63, g = tid >> 6;
  float mx = -1e30f;
#pragma unroll
  for (int k = 0; k < 16; ++k)
    mx = fmaxf(mx, bf2f(zbf[((size_t)b * N_ + n0 + g + 4 * k) * 128 + e]));
  red[g][e] = mx;
  __syncthreads();
  if (tid < 64)
    mppA[((size_t)b * 64 + blockIdx.x) * 64 + tid] =
        fmaxf(fmaxf(red[0][tid], red[1][tid]), fmaxf(red[2][tid], red[3][tid]));
}

__global__ __launch_bounds__(256) void y2_kernel(const unsigned short* __restrict__ s2bf,
                                                 const unsigned short* __restrict__ a1t,
                                                 unsigned short* __restrict__ zbf,
                                                 float* __restrict__ mppB) {
  __shared__ f4 red[4][4][16];
  y2_phase(s2bf, a1t, zbf, mppB, red, blockIdx.y, blockIdx.x, threadIdx.x);
}

// ---------------------------------------------------------------------------
// ca2: full channel attention, one block per batch. mppA, mppB [B][64][64].
// ---------------------------------------------------------------------------
__global__ __launch_bounds__(256) void ca2_kernel(const float* __restrict__ mppA,
                                                  const float* __restrict__ mppB,
                                                  const float* __restrict__ fc1,
                                                  const float* __restrict__ fc2,
                                                  float* __restrict__ vbuf) {
  __shared__ f4 red4[256];
  __shared__ float mpl[128];
  __shared__ float red2[8][33];
  __shared__ float hl[8];
  int b = blockIdx.x, t = threadIdx.x;
  {
    const f4* src = (const f4*)(mppA + (size_t)b * 64 * 64);
    f4 m = src[t];
    m = max4(m, src[t + 256]);
    m = max4(m, src[t + 512]);
    m = max4(m, src[t + 768]);
    red4[t] = m;
  }
  __syncthreads();
  if (t < 16) {
    f4 m = red4[t];
#pragma unroll
    for (int j = 1; j < 16; ++j) m = max4(m, red4[t + 16 * j]);
    *(f4*)&mpl[t * 4] = m;
  }
  __syncthreads();
  {
    const f4* src = (const f4*)(mppB + (size_t)b * 64 * 64);
    f4 m = src[t];
    m = max4(m, src[t + 256]);
    m = max4(m, src[t + 512]);
    m = max4(m, src[t + 768]);
    red4[t] = m;
  }
  __syncthreads();
  if (t < 16) {
    f4 m = red4[t];
#pragma unroll
    for (int j = 1; j < 16; ++j) m = max4(m, red4[t + 16 * j]);
    *(f4*)&mpl[64 + t * 4] = m;
  }
  __syncthreads();
  {
    int r = t >> 5, j = t & 31;
    const f4 mv = *(const f4*)&mpl[j * 4];
    const f4 wv = *(const f4*)(fc1 + r * 128 + j * 4);
    red2[r][j] = mv.x * wv.x + mv.y * wv.y + mv.z * wv.z + mv.w * wv.w;
  }
  __syncthreads();
  if (t < 8) {
    float s = 0.f;
#pragma unroll
    for (int j = 0; j < 32; ++j) s += red2[t][j];
    hl[t] = fmaxf(s, 0.f);
  }
  __syncthreads();
  if (t < 128) {
    float s = 0.f;
    const float* f2r = fc2 + t * 8;
#pragma unroll
    for (int r = 0; r < 8; ++r) s += hl[r] * f2r[r];
    vbuf[b * 128 + t] = 1.f + 1.f / (1.f + __expf(-s));
  }
}

// ---------------------------------------------------------------------------
// final 1x1 conv via MFMA, LDS-free (r18, unchanged):
// out[b][o][n] = sum_e zbf[n][e] * (v[e]*cw[o][e]) + conv_b[o]
// ---------------------------------------------------------------------------
__global__ __launch_bounds__(256) void conv_kernel(const unsigned short* __restrict__ zbf,
                                                   const float* __restrict__ vbuf,
                                                   const float* __restrict__ conv_w,
                                                   const float* __restrict__ conv_b,
                                                   float* __restrict__ out) {
  int b = blockIdx.y, n0 = blockIdx.x * 32, tid = threadIdx.x;
  int wave = tid >> 6, lane = tid & 63, l16 = lane & 15, lq = lane >> 4;
  const float* cwr = conv_w + (size_t)(16 * wave + l16) * 128 + lq * 8;
  const float* vbr = vbuf + b * 128 + lq * 8;
  frag aw[4];
#pragma unroll
  for (int ks = 0; ks < 4; ++ks) {
    f4 c0 = *(const f4*)(cwr + ks * 32);
    f4 c1 = *(const f4*)(cwr + ks * 32 + 4);
    f4 v0 = *(const f4*)(vbr + ks * 32);
    f4 v1 = *(const f4*)(vbr + ks * 32 + 4);
    aw[ks] = pk8(c0 * v0, c1 * v1);
  }
  f32x4 acc[2];
#pragma unroll
  for (int ng = 0; ng < 2; ++ng) acc[ng] = (f32x4){0.f, 0.f, 0.f, 0.f};
#pragma unroll
  for (int ng = 0; ng < 2; ++ng) {
    const unsigned short* zr = zbf + ((size_t)b * N_ + n0 + ng * 16 + l16) * 128;
#pragma unroll
    for (int ks = 0; ks < 4; ++ks) {
      frag bz = *(const frag*)(zr + ks * 32 + lq * 8);
      acc[ng] = __builtin_amdgcn_mfma_f32_16x16x32_bf16(aw[ks], bz, acc[ng], 0, 0, 0);
    }
  }
#pragma unroll
  for (int r = 0; r < 4; ++r) {
    int o = 16 * wave + 4 * lq + r;
    float bias = conv_b[o];
#pragma unroll
    for (int ng = 0; ng < 2; ++ng)
      out[((size_t)(b * C_ + o)) * N_ + n0 + ng * 16 + l16] = acc[ng][r] + bias;
  }
}

// ---------------------------------------------------------------------------
extern "C" void kernel_launch(void* const* d_in, const int* in_sizes, int n_in,
                              void* d_out, int out_size, void* d_ws, size_t ws_size,
                              hipStream_t stream) {
  const float* x1      = (const float*)d_in[0];
  const float* x2      = (const float*)d_in[1];
  const float* weight  = (const float*)d_in[2];
  const float* weight2 = (const float*)d_in[3];
  const float* fc1     = (const float*)d_in[4];
  const float* fc2     = (const float*)d_in[5];
  const float* conv_w  = (const float*)d_in[6];
  const float* conv_b  = (const float*)d_in[7];
  float* out = (float*)d_out;

  // workspace layout
  char* ws = (char*)d_ws;
  unsigned short* a1t = (unsigned short*)(ws + 0);          // 2 MB bf16 [B][N][C]
  unsigned short* a2t = (unsigned short*)(ws + 2097152);    // 2 MB bf16 [B][N][C]
  // post-attn aliases of the a2t region:
  float* mppA = (float*)(ws + 2097152);                     // 64 KB [B][64][64]
  float* mppB = (float*)(ws + 2162688);                     // 64 KB [B][64][64]
  unsigned short* s2bf = (unsigned short*)(ws + 2293760);   // 32 KB bf16 [B][C][C]
  unsigned short* vT  = (unsigned short*)(ws + 4194304);    // 2 MB bf16 [B][C][N]
  unsigned short* zbf = (unsigned short*)(ws + 6291456);    // 4 MB bf16 [B][N][2C]
  float* cxp  = (float*)(ws + 10485760);                    // 4 MB fp32 [B][64][4096]
  float* cx   = (float*)(ws + 14680064);                    // 64 KB [B][64*64] (cxT: [d][c])
  float* vbuf = (float*)(ws + 14745600);                    // 2 KB  [B][128]
  unsigned short* Opart = (unsigned short*)(ws + 14764544); // 8 MB bf16 [B][4][N][64]
  float* ml   = (float*)(ws + 23153152);                    // 512 KB [B][4][N][2]
  const bool seg4 = ws_size >= 23677440ull;

  prep_kernel<<<dim3(64, 4), 256, 0, stream>>>(x1, x2, weight, a1t, a2t, vT, cxp);
  cxred_kernel<<<dim3(64), 256, 0, stream>>>(cxp, cx);
  if (seg4) {
    attn_kernel<4><<<dim3(32, 4, 4), 512, 0, stream>>>(a1t, a2t, vT, zbf, Opart, ml);
    s2bf_kernel<<<dim3(4), 256, 0, stream>>>(cx, weight2, s2bf);    // a2t dead now
    combineY2_kernel<4><<<dim3(64, 4), 256, 0, stream>>>(Opart, ml, s2bf, a1t, zbf, mppA, mppB);
  } else {
    attn_kernel<1><<<dim3(32, 4), 512, 0, stream>>>(a1t, a2t, vT, zbf, nullptr, nullptr);
    s2bf_kernel<<<dim3(4), 256, 0, stream>>>(cx, weight2, s2bf);
    mpA_kernel<<<dim3(64, 4), 256, 0, stream>>>(zbf, mppA);
    y2_kernel<<<dim3(64, 4), 256, 0, stream>>>(s2bf, a1t, zbf, mppB);
  }
  ca2_kernel<<<dim3(4), 256, 0, stream>>>(mppA, mppB, fc1, fc2, vbuf);
  conv_kernel<<<dim3(128, 4), 256, 0, stream>>>(zbf, vbuf, conv_w, conv_b, out);
}